// Round 9
// baseline (641.007 us; speedup 1.0000x reference)
//
#include <hip/hip_runtime.h>

#define NN   16384
#define NE   262144
#define NB   32
#define H    128
#define NH   (NN*H)
#define RBF  50
#define TM   64
#define KC   64
#define KP   72     // node-kernel LDS panel pitch (u16)
#define HBP  136    // edge reduce-buffer pitch (u16): 272 B rows
#define CHW  9216   // edge weight chunk: [128 rows][72 u16] (64 k + 8 pad)
#define LT2  115712 // packed edge weights per layer (u16)
#define LN_  49152  // packed node weights per layer (u16)
#define NG   196608 // offset of global node weights in packn
#define EPB  128    // edges per block (k_edge)
#define WEV  32     // edges per wave  (k_edge)
#define TT   4096   // distance-table resolution
#define PB   32     // k_pool blocks per batch

typedef unsigned short u16;
typedef short bf16x8 __attribute__((ext_vector_type(8)));
typedef float f32x4 __attribute__((ext_vector_type(4)));
typedef float f32x16 __attribute__((ext_vector_type(16)));
typedef unsigned u32x2 __attribute__((ext_vector_type(2)));

#if defined(__has_builtin)
#if __has_builtin(__builtin_amdgcn_cvt_pk_bf16_f32)
#define HAS_PK_BF16 1
#endif
#if __has_builtin(__builtin_amdgcn_permlane32_swap)
#define HAS_PLSWAP 1
#endif
#endif

__device__ __forceinline__ float sigmoidf_(float v){ return 1.0f/(1.0f + __expf(-v)); }
__device__ __forceinline__ float siluf_(float v){ return v * sigmoidf_(v); }
__device__ __forceinline__ u16 f2bf(float f){
  unsigned u = __float_as_uint(f);
  return (u16)((u + 0x7FFFu + ((u>>16)&1u)) >> 16);
}
__device__ __forceinline__ float bf2f(u16 v){ return __uint_as_float(((unsigned)v)<<16); }
__device__ __forceinline__ unsigned pk2(float a, float b){
#ifdef HAS_PK_BF16
  typedef __bf16 v2bf __attribute__((ext_vector_type(2)));
  v2bf v = __builtin_amdgcn_cvt_pk_bf16_f32(a, b);
  return __builtin_bit_cast(unsigned, v);
#else
  return (unsigned)f2bf(a) | ((unsigned)f2bf(b)<<16);
#endif
}
__device__ __forceinline__ uint2 pack4(float a, float b, float c, float d){
  uint2 r; r.x = pk2(a,b); r.y = pk2(c,d); return r;
}
__device__ __forceinline__ float blo(unsigned u){ return bf2f((u16)(u & 0xffffu)); }
__device__ __forceinline__ float bhi(unsigned u){ return bf2f((u16)(u >> 16)); }

// fragment-order permutation: perm[hi*64+16t+4u+j] = orig[32t+4hi+8u+j]
__device__ __forceinline__ int permc(int c){
  return ((c>>2)&1)*64 + ((c>>5)&3)*16 + ((c>>3)&3)*4;
}

// ---- permlane32_swap
__device__ __forceinline__ void plswap(unsigned a, unsigned b, unsigned &x, unsigned &y){
#ifdef HAS_PLSWAP
  u32x2 q = __builtin_amdgcn_permlane32_swap(a, b, false, false);
  x = q.x; y = q.y;
#else
  int l_ = (int)(threadIdx.x & 63);
  unsigned as_ = __shfl(a, l_^32);
  unsigned bs_ = __shfl(b, l_^32);
  x = (l_ < 32) ? a : bs_;
  y = (l_ < 32) ? as_ : b;
#endif
}

// ---- pack 16 f32 (one 32x32 C tile per lane) into two B-frags
__device__ __forceinline__ void pack_frags(const float* v, uint4& f0, uint4& f1){
  unsigned P0 = pk2(v[0],v[1]),   P1 = pk2(v[2],v[3]);
  unsigned P2 = pk2(v[4],v[5]),   P3 = pk2(v[6],v[7]);
  unsigned P4 = pk2(v[8],v[9]),   P5 = pk2(v[10],v[11]);
  unsigned P6 = pk2(v[12],v[13]), P7 = pk2(v[14],v[15]);
  unsigned x0,y0,x1,y1,x2,y2,x3,y3;
  plswap(P0,P2,x0,y0); plswap(P1,P3,x1,y1);
  plswap(P4,P6,x2,y2); plswap(P5,P7,x3,y3);
  f0.x=x0; f0.y=x1; f0.z=y0; f0.w=y1;
  f1.x=x2; f1.y=x3; f1.z=y2; f1.w=y3;
}

// ---- global->LDS direct staging (k_table only)
__device__ __forceinline__ void gll16(const u16* g, u16* l){
  __builtin_amdgcn_global_load_lds((const __attribute__((address_space(1))) void*)g,
                                   (__attribute__((address_space(3))) void*)l, 16, 0, 0);
}
__device__ __forceinline__ void gll4(const u16* g, u16* l){
  __builtin_amdgcn_global_load_lds((const __attribute__((address_space(1))) void*)g,
                                   (__attribute__((address_space(3))) void*)l, 4, 0, 0);
}

// ---------------------------------------------------------------- utility
__global__ void k_zero(float* __restrict__ p, int n){
  int i = blockIdx.x*256 + threadIdx.x; if (i < n) p[i] = 0.f;
}
__global__ void k_zero_i(int* __restrict__ p, int n){
  int i = blockIdx.x*256 + threadIdx.x; if (i < n) p[i] = 0;
}
__global__ void k_embed(const int* __restrict__ z, const float* __restrict__ emb,
                        float* __restrict__ x, u16* __restrict__ xb){
  int i = blockIdx.x*256 + threadIdx.x;
  int n = i >> 7, h = i & 127;
  float v = emb[z[n]*H + h];
  x[i] = v; xb[i] = f2bf(v);
}

// ---------------------------------------------------------------- weight packing
// Edge layout per layer: chunks c=0..6 of [128][72] (LDS layout, k_table):
// 0:ee1 1,2:ee2 3,4:m1e 5,6:gate.
// msg2 @64512: FRAGMENT order (32x32): off=((c*16+s*4+t)*64+l)*8+j,
//   col=t*32+(l&31), k=c*64+s*16+(l>>5)*8+j.
// m1d @82944, m1s @99328: FRAGMENT order (16x16): off=((((p*2+ks)*8+t)*64+l)*8+j,
//   col=t*16+(l&15), k=p*64+ks*32+(l>>4)*8+j.
__global__ void k_pack(const float* __restrict__ ee_w1, const float* __restrict__ ee_w2,
                       const float* __restrict__ msg_w1, const float* __restrict__ msg_w2,
                       const float* __restrict__ gate_w, u16* __restrict__ out){
  int idx = blockIdx.x*256 + threadIdx.x;
  int l = blockIdx.y;
  if (idx >= LT2) return;
  u16* o = out + (size_t)l*LT2;
  float v = 0.f;
  if (idx < 64512){
    int c = idx / CHW, r = idx % CHW, row = r / 72, col = r % 72;
    if (col < 64){
      if (c == 0)      v = (col < RBF) ? ee_w1[(size_t)l*RBF*H + col*H + row] : 0.f;
      else if (c <= 2) v = ee_w2 [(size_t)l*H*H + (64*(c-1)+col)*H + row];
      else if (c <= 4) v = msg_w1[(size_t)l*3*H*H + (256 + 64*(c-3)+col)*H + row];
      else             v = gate_w[(size_t)l*H*H + (64*(c-5)+col)*H + row];
    }
  } else if (idx < 64512 + 16384){
    int r = idx - 64512; int c = r >> 13; int rr = r & 8191;
    int jj = rr&7, ll = (rr>>3)&63, tt = (rr>>9)&3, ss = (rr>>11)&3;
    int col = tt*32 + (ll&31);
    int k = c*64 + ss*16 + (ll>>5)*8 + jj;
    v = msg_w2[(size_t)l*H*H + k*H + col];
  } else if (idx < 82944){
    v = 0.f;
  } else if (idx < 99328){
    int j2 = idx - 82944;
    int jj=j2&7, ll=(j2>>3)&63, tt=(j2>>9)&7, ks=(j2>>12)&1, pp=j2>>13;
    int k = pp*64 + ks*32 + (ll>>4)*8 + jj;
    int col = tt*16 + (ll&15);
    v = msg_w1[(size_t)l*3*H*H + k*H + col];
  } else {
    int j2 = idx - 99328;
    int jj=j2&7, ll=(j2>>3)&63, tt=(j2>>9)&7, ks=(j2>>12)&1, pp=j2>>13;
    int k = pp*64 + ks*32 + (ll>>4)*8 + jj;
    int col = tt*16 + (ll&15);
    v = msg_w1[(size_t)l*3*H*H + (128+k)*H + col];
  }
  o[idx] = f2bf(v);
}

// node weights: ALL in 16x16 fragment order (same region offsets as before).
__global__ void k_packn(const float* __restrict__ upd_w1, const float* __restrict__ upd_w2,
                        const float* __restrict__ ro_w1, const float* __restrict__ ro_w2,
                        const float* __restrict__ pn_w, const float* __restrict__ gp_w1,
                        u16* __restrict__ out){
  int idx = blockIdx.x*256 + threadIdx.x;
  if (idx >= NG + 65536) return;
  float v;
  if (idx < NG){
    int l = idx / LN_, j = idx % LN_;
    if (j < 32768){
      int jj=j&7, ll=(j>>3)&63, tt=(j>>9)&7, ks=(j>>12)&1, pp=j>>13;
      int k = pp*64 + ks*32 + (ll>>4)*8 + jj;
      int col = tt*16 + (ll&15);
      v = upd_w1[(size_t)l*256*H + k*H + col];
    } else {
      int j2 = j - 32768;
      int jj=j2&7, ll=(j2>>3)&63, tt=(j2>>9)&7, ks=(j2>>12)&1, pp=j2>>13;
      int k = pp*64 + ks*32 + (ll>>4)*8 + jj;
      int col = tt*16 + (ll&15);
      v = upd_w2[(size_t)l*H*H + k*H + col];
    }
  } else {
    int j = idx - NG; int m = j >> 14; int j2 = j & 16383;
    int jj=j2&7, ll=(j2>>3)&63, tt=(j2>>9)&7, ks=(j2>>12)&1, pp=j2>>13;
    int k = pp*64 + ks*32 + (ll>>4)*8 + jj;
    int col = tt*16 + (ll&15);
    const float* W = (m==0) ? ro_w1 : (m==1) ? ro_w2 : (m==2) ? pn_w : gp_w1;
    v = W[k*H + col];
  }
  out[idx] = f2bf(v);
}

// ---------------------------------------------------------------- edge sort by dst
__global__ void k_hist(const int* __restrict__ dstv, int* __restrict__ cnt){
  int e = blockIdx.x*256 + threadIdx.x;
  if (e < NE) atomicAdd(&cnt[dstv[e]], 1);
}
__global__ __launch_bounds__(1024)
void k_scan(int* __restrict__ cnt, int* __restrict__ start){
  __shared__ int ps[1024];
  int tid = threadIdx.x;
  int base = tid*16;
  int loc[16]; int s = 0;
#pragma unroll
  for (int i=0;i<16;i++){ loc[i] = s; s += cnt[base+i]; }
  ps[tid] = s; __syncthreads();
  for (int off=1; off<1024; off<<=1){
    int v = (tid>=off) ? ps[tid-off] : 0;
    __syncthreads();
    ps[tid] += v;
    __syncthreads();
  }
  int pre = (tid>0) ? ps[tid-1] : 0;
#pragma unroll
  for (int i=0;i<16;i++){ int v = pre + loc[i]; start[base+i] = v; cnt[base+i] = v; }
  if (tid == 0) start[NN] = NE;
}
__global__ void k_scatter(const int* __restrict__ srcv, const int* __restrict__ dstv,
                          int* __restrict__ cursor, int* __restrict__ src_s,
                          int* __restrict__ dst_s){
  int e = blockIdx.x*256 + threadIdx.x;
  if (e >= NE) return;
  int d = dstv[e];
  int p = atomicAdd(&cursor[d], 1);
  src_s[p] = srcv[e]; dst_s[p] = d;
}

// ---------------------------------------------------------------- distance tables
#define TMFMA(CHP, AOFF, ACC) \
  _Pragma("unroll") \
  for (int ks_=0; ks_<64; ks_+=32){ \
    bf16x8 bf_ = *(const bf16x8*)&Ab[wrow + l15][(AOFF) + ks_ + q8]; \
    _Pragma("unroll") \
    for (int t_=0;t_<8;t_++){ \
      bf16x8 wf_ = *(const bf16x8*)&(CHP)[(t_*16 + l15)*72 + ks_ + q8]; \
      ACC[t_] = __builtin_amdgcn_mfma_f32_16x16x32_bf16(wf_, bf_, ACC[t_], 0, 0, 0); \
    } \
  }

__global__ __launch_bounds__(256)
void k_table(const u16* __restrict__ packw, const float* __restrict__ widths,
             const float* __restrict__ ee_b1, const float* __restrict__ ee_b2,
             const float* __restrict__ gate_b,
             u16* __restrict__ m1t, u16* __restrict__ gt){
  __shared__ u16 CH[7][CHW];        // 129 KB: chunks 0..6
  __shared__ u16 Ab[TM][2*KP];      // 18.4 KB
  __shared__ float b1s[H], b2s[H], bgs[H];
  const int tid = threadIdx.x;
  const int wave = tid>>6, l = tid&63, l15 = l&15, quad = l>>4;
  const int wrow = wave*16, q8 = quad*8;
  const int lyr = blockIdx.y;
  const int rowbase = blockIdx.x*TM;
  const u16* pw = packw + (size_t)lyr*LT2;
  if (tid < H){ b1s[tid] = ee_b1[lyr*H+tid]; b2s[tid] = ee_b2[lyr*H+tid];
                bgs[tid] = gate_b[lyr*H+tid]; }
#pragma unroll
  for (int c=0;c<7;c++){
    const u16* gs = pw + (size_t)c*CHW;
    u16* ls = &CH[c][0];
#pragma unroll
    for (int i=0;i<4;i++) gll16(gs + (i*256+tid)*8, ls + (i*256+tid)*8);
#pragma unroll
    for (int i=0;i<2;i++) gll4(gs + 8192 + (i*256+tid)*2, ls + 8192 + (i*256+tid)*2);
  }
  // rbf rows
  {
    int r = tid>>2, k0 = (tid&3)*16;
    float d = 5.0f*(float)(rowbase + r)/(float)(TT-1);
    float cut = (d < 5.0f) ? 0.5f*(__cosf(0.62831853f*d)+1.0f) : 0.0f;
    unsigned vv[8];
#pragma unroll
    for (int j=0;j<8;j++){
      int ka = k0+2*j, kb = ka+1;
      float wa = widths[ka < RBF ? ka : 0], wb = widths[kb < RBF ? kb : 0];
      float ta = d - 0.10204082f*(float)ka;
      float tb = d - 0.10204082f*(float)kb;
      float va = (ka<RBF)? __expf(-(1.0f/(2.0f*wa*wa))*ta*ta)*cut : 0.f;
      float vb = (kb<RBF)? __expf(-(1.0f/(2.0f*wb*wb))*tb*tb)*cut : 0.f;
      vv[j] = pk2(va,vb);
    }
    uint4 u0; u0.x=vv[0]; u0.y=vv[1]; u0.z=vv[2]; u0.w=vv[3];
    uint4 u1; u1.x=vv[4]; u1.y=vv[5]; u1.z=vv[6]; u1.w=vv[7];
    *(uint4*)&Ab[r][k0]   = u0;
    *(uint4*)&Ab[r][k0+8] = u1;
  }
  __syncthreads();
  f32x4 acc[8];
#pragma unroll
  for (int t=0;t<8;t++) acc[t] = (f32x4)(0.f);
  TMFMA(CH[0], 0, acc)
  const int s = rowbase + wrow + l15;
#pragma unroll
  for (int t=0;t<8;t++){
    int co = t*16 + quad*4;
    int po = (co>>6)*KP + (co&63);
    *(uint2*)&Ab[wrow + l15][po] = pack4(
      siluf_(acc[t][0]+b1s[co]),   siluf_(acc[t][1]+b1s[co+1]),
      siluf_(acc[t][2]+b1s[co+2]), siluf_(acc[t][3]+b1s[co+3]));
  }
#pragma unroll
  for (int t=0;t<8;t++) acc[t] = (f32x4)(0.f);
  TMFMA(CH[1], 0, acc)
  TMFMA(CH[2], KP, acc)
#pragma unroll
  for (int t=0;t<8;t++){
    int co = t*16 + quad*4;
    int po = (co>>6)*KP + (co&63);
    *(uint2*)&Ab[wrow + l15][po] = pack4(
      acc[t][0]+b2s[co], acc[t][1]+b2s[co+1], acc[t][2]+b2s[co+2], acc[t][3]+b2s[co+3]);
  }
#pragma unroll
  for (int t=0;t<8;t++) acc[t] = (f32x4)(0.f);
  TMFMA(CH[3], 0, acc)
  TMFMA(CH[4], KP, acc)
#pragma unroll
  for (int t=0;t<8;t++){
    int co = t*16 + quad*4;
    *(uint2*)&m1t[((size_t)lyr*TT + s)*H + permc(co)] =
      pack4(acc[t][0], acc[t][1], acc[t][2], acc[t][3]);
  }
#pragma unroll
  for (int t=0;t<8;t++) acc[t] = (f32x4)(0.f);
  TMFMA(CH[5], 0, acc)
  TMFMA(CH[6], KP, acc)
#pragma unroll
  for (int t=0;t<8;t++){
    int co = t*16 + quad*4;
    *(uint2*)&gt[((size_t)lyr*TT + s)*H + permc(co)] = pack4(
      sigmoidf_(acc[t][0]+bgs[co]),   sigmoidf_(acc[t][1]+bgs[co+1]),
      sigmoidf_(acc[t][2]+bgs[co+2]), sigmoidf_(acc[t][3]+bgs[co+3]));
  }
}

// ---------------------------------------------------------------- FUSED edge pipeline
// R17: table-driven edges, msg2 weights FRAGMENT-packed -> direct global->VGPR
// loads (no weight LDS, no staging barriers). LDS = Sb reduce staging only.

#define ZACC(A) { _Pragma("unroll") for (int z_=0;z_<4;z_++) A[z_] = (f32x16)(0.f); }
#define SEL2(V, UF) (((UF)&1) ? make_uint2((V).z,(V).w) : make_uint2((V).x,(V).y))
#define DWEL(r) (((r)&3)==0 ? dw[(r)>>2].x : ((r)&3)==1 ? dw[(r)>>2].y : \
                 ((r)&3)==2 ? dw[(r)>>2].z : dw[(r)>>2].w)

__global__ __launch_bounds__(256, 3)
void k_edge(const int* __restrict__ src_s, const int* __restrict__ dst_s,
            const float* __restrict__ pos,
            const u16* __restrict__ y1b, const u16* __restrict__ y2b,
            const u16* __restrict__ pw,        // msg2 frag-packed (packw + l*LT2 + 64512)
            const u16* __restrict__ m1t, const u16* __restrict__ gt,
            const float* __restrict__ b_m2, float* __restrict__ aggr){
  __shared__ u16 SB[4][WEV][HBP];   // 34.8 KB wave-local reduce staging
  __shared__ float BM[H];
  const int tid = threadIdx.x;
  const int wave = tid>>6, l = tid&63, l31 = l&31, hi = l>>5;
  const int ebase = blockIdx.x*EPB + wave*WEV;
  const int eid   = ebase + l31;
  u16 (*Sb)[HBP] = SB[wave];
  if (tid < H) BM[tid] = b_m2[tid];

  const int esrc = src_s[eid], edst = dst_s[eid];
  float dx = pos[3*edst]   - pos[3*esrc];
  float dy = pos[3*edst+1] - pos[3*esrc+1];
  float dz = pos[3*edst+2] - pos[3*esrc+2];
  float dist = sqrtf(dx*dx + dy*dy + dz*dz);
  float uu = fminf(dist, 5.0f) * ((float)(TT-1)/5.0f);
  int i0 = (int)uu; if (i0 > TT-2) i0 = TT-2;
  float w = uu - (float)i0;

  // permuted-layout gathers: each lane reads its 128B half-row as 8 uint4
  const u16* yp1 = y1b + (size_t)edst*H + hi*64;
  const u16* yp2 = y2b + (size_t)esrc*H + hi*64;
  const u16* mp  = m1t + (size_t)i0*H  + hi*64;
  uint4 Y1[8], Y2[8], M0[8], M1[8];
#pragma unroll
  for (int i=0;i<8;i++){
    Y1[i] = *(const uint4*)&yp1[i*8];
    Y2[i] = *(const uint4*)&yp2[i*8];
    M0[i] = *(const uint4*)&mp[i*8];
    M1[i] = *(const uint4*)&mp[H + i*8];
  }

  __syncthreads();                     // BM ready (only cross-wave dependency)

  // msg hidden = silu(lerp(m1e) + y1 + y2) -> B-frags
  uint4 fmh[8];
#pragma unroll
  for (int tf=0;tf<4;tf++){
    float v_[16];
#pragma unroll
    for (int uf=0;uf<4;uf++){
      int iv = 2*tf + (uf>>1);
      uint2 a1 = SEL2(Y1[iv],uf), a2 = SEL2(Y2[iv],uf);
      uint2 m0 = SEL2(M0[iv],uf), m1 = SEL2(M1[iv],uf);
      float p0 = blo(m0.x), p1 = bhi(m0.x), p2 = blo(m0.y), p3 = bhi(m0.y);
      float q0 = blo(m1.x), q1 = bhi(m1.x), q2 = blo(m1.y), q3 = bhi(m1.y);
      v_[4*uf+0] = siluf_(fmaf(w, q0-p0, p0) + blo(a1.x) + blo(a2.x));
      v_[4*uf+1] = siluf_(fmaf(w, q1-p1, p1) + bhi(a1.x) + bhi(a2.x));
      v_[4*uf+2] = siluf_(fmaf(w, q2-p2, p2) + blo(a1.y) + blo(a2.y));
      v_[4*uf+3] = siluf_(fmaf(w, q3-p3, p3) + bhi(a1.y) + bhi(a2.y));
    }
    pack_frags(v_, fmh[2*tf], fmh[2*tf+1]);
  }

  // gate rows (issued now, consumed after the MFMAs)
  const u16* gp = gt + (size_t)i0*H + hi*64;
  uint4 G0[8], G1[8];
#pragma unroll
  for (int i=0;i<8;i++){
    G0[i] = *(const uint4*)&gp[i*8];
    G1[i] = *(const uint4*)&gp[H + i*8];
  }

  // msg2 GEMM: W fragments direct from global (frag-packed, L2-resident)
  f32x16 acc[4];
  ZACC(acc)
#pragma unroll
  for (int c=0;c<2;c++){
#pragma unroll
    for (int s_=0;s_<4;s_++){
      bf16x8 bf_ = __builtin_bit_cast(bf16x8, fmh[c*4+s_]);
#pragma unroll
      for (int t_=0;t_<4;t_++){
        bf16x8 wf_ = *(const bf16x8*)&pw[((c*16 + s_*4 + t_)*64 + l)*8];
        acc[t_] = __builtin_amdgcn_mfma_f32_32x32x16_bf16(wf_, bf_, acc[t_], 0, 0, 0);
      }
    }
  }

  // gated message -> Sb (bf16 pairs)
#pragma unroll
  for (int tf=0;tf<4;tf++){
#pragma unroll
    for (int uf=0;uf<4;uf++){
      int iv = 2*tf + (uf>>1);
      int co = 32*tf + 4*hi + 8*uf;
      float4 bm = *(const float4*)&BM[co];
      uint2 a0 = SEL2(G0[iv],uf), a1 = SEL2(G1[iv],uf);
      float g0 = fmaf(w, blo(a1.x)-blo(a0.x), blo(a0.x));
      float g1 = fmaf(w, bhi(a1.x)-bhi(a0.x), bhi(a0.x));
      float g2 = fmaf(w, blo(a1.y)-blo(a0.y), blo(a0.y));
      float g3 = fmaf(w, bhi(a1.y)-bhi(a0.y), bhi(a0.y));
      float m0 = (acc[tf][4*uf+0]+bm.x)*g0;
      float m1 = (acc[tf][4*uf+1]+bm.y)*g1;
      float m2 = (acc[tf][4*uf+2]+bm.z)*g2;
      float m3 = (acc[tf][4*uf+3]+bm.w)*g3;
      *(uint2*)&Sb[l31][co] = pack4(m0, m1, m2, m3);
    }
  }

  // ---- wave-local segmented reduce (dst-sorted): 2 cols/lane over 32 rows
  {
    int4 dw[8];
#pragma unroll
    for (int i=0;i<8;i++) dw[i] = *(const int4*)&dst_s[ebase + 4*i];
    int c0 = l*2;
    float a0 = 0.f, a1 = 0.f;
    int cur = dw[0].x;
#pragma unroll
    for (int r=0;r<32;r++){
      int d = DWEL(r);
      if (d != cur){
        atomicAdd(&aggr[(size_t)cur*H + c0],     a0);
        atomicAdd(&aggr[(size_t)cur*H + c0 + 1], a1);
        a0 = 0.f; a1 = 0.f; cur = d;
      }
      unsigned pv = *(const unsigned*)&Sb[r][c0];
      a0 += blo(pv); a1 += bhi(pv);
    }
    atomicAdd(&aggr[(size_t)cur*H + c0],     a0);
    atomicAdd(&aggr[(size_t)cur*H + c0 + 1], a1);
  }
}

// ---------------------------------------------------------------- node MFMA kernels
// R17: W operand loaded global->VGPR from FRAGMENT-packed weights (no W LDS).
// LDS = Ab only -> 2 blocks/CU. h/ae re-frag is wave-private (no barriers).

// GEMM over NP 64-K panels: A from LDS (panel base APB), W frag-packed global.
#define GFMFMA(GW, APB, NP, ACC) \
  _Pragma("unroll") \
  for (int p_=0;p_<(NP);p_++){ \
    _Pragma("unroll") \
    for (int ks_=0;ks_<2;ks_++){ \
      bf16x8 bf_ = *(const bf16x8*)&Ab[wrow + l15][((APB)+p_)*KP + ks_*32 + q8]; \
      _Pragma("unroll") \
      for (int t_=0;t_<8;t_++){ \
        bf16x8 wf_ = *(const bf16x8*)&(GW)[((((p_*2+ks_)*8)+t_)*64 + l)*8]; \
        ACC[t_] = __builtin_amdgcn_mfma_f32_16x16x32_bf16(wf_, bf_, ACC[t_], 0, 0, 0); \
      } \
    } \
  }

#define NSTAGE_A(AB, GSRC, P) \
  _Pragma("unroll") \
  for (int i_=0;i_<2;i_++){ \
    int o_ = tid*2 + i_; int r_ = o_>>3, ko_ = (o_&7)*8; \
    *(uint4*)&AB[r_][(P)*KP + ko_] = *(const uint4*)((GSRC) + (size_t)r_*H + (P)*64 + ko_); \
  }

#define NSTAGE_AF(AB, GSRC, P) \
  _Pragma("unroll") \
  for (int i_=0;i_<2;i_++){ \
    int o_ = tid*2 + i_; int r_ = o_>>3, ko_ = (o_&7)*8; \
    const float* rp_ = (GSRC) + (size_t)r_*H + (P)*64 + ko_; \
    float4 f0_ = *(const float4*)rp_; \
    float4 f1_ = *(const float4*)(rp_ + 4); \
    uint4 pk_; \
    pk_.x = pk2(f0_.x, f0_.y); pk_.y = pk2(f0_.z, f0_.w); \
    pk_.z = pk2(f1_.x, f1_.y); pk_.w = pk2(f1_.z, f1_.w); \
    *(uint4*)&AB[r_][(P)*KP + ko_] = pk_; \
  }

// standalone y1 = x@W1d + b_m1 ; y2 = x@W1s  (layer 0 only) [permuted y output]
__global__ __launch_bounds__(256, 2)
void k_y12(const u16* __restrict__ xb, const u16* __restrict__ Wd,
           const u16* __restrict__ Ws, const float* __restrict__ b1,
           u16* __restrict__ y1, u16* __restrict__ y2){
  __shared__ u16 Ab[TM][2*KP];
  __shared__ float bls[H];
  const int tid = threadIdx.x;
  const int wave = tid>>6, l = tid&63, l15 = l&15, quad = l>>4;
  const int wrow = wave*16, q8 = quad*8;
  const int rowbase = blockIdx.x*TM;
  if (tid < H) bls[tid] = b1[tid];
  NSTAGE_A(Ab, xb + (size_t)rowbase*H, 0) NSTAGE_A(Ab, xb + (size_t)rowbase*H, 1)
  __syncthreads();
  f32x4 a1[8], a2[8];
#pragma unroll
  for (int t=0;t<8;t++){ a1[t] = (f32x4)(0.f); a2[t] = (f32x4)(0.f); }
  GFMFMA(Wd, 0, 2, a1)
  GFMFMA(Ws, 0, 2, a2)
  const int node = rowbase + wrow + l15;
#pragma unroll
  for (int t=0;t<8;t++){
    int co = t*16 + quad*4;
    int pc = permc(co);
    *(uint2*)&y1[(size_t)node*H + pc] = pack4(
      a1[t][0]+bls[co], a1[t][1]+bls[co+1], a1[t][2]+bls[co+2], a1[t][3]+bls[co+3]);
    *(uint2*)&y2[(size_t)node*H + pc] = pack4(
      a2[t][0], a2[t][1], a2[t][2], a2[t][3]);
  }
}

// FUSED per-layer node kernel: upd1 (K=256) -> silu -> upd2 -> residual+LN
// (-> ADDSUM sumf/3, last layer emits bf16 mean) -> optional next-layer y1/y2.
template<int ADDSUM, int DOY12>
__global__ __launch_bounds__(256, 2)
void k_upd(float* __restrict__ aggr, const u16* __restrict__ xin,
           const u16* __restrict__ W1g, const float* __restrict__ b1,
           const u16* __restrict__ W2g, const float* __restrict__ b2,
           const float* __restrict__ lng, const float* __restrict__ lnb,
           float* __restrict__ x, float* __restrict__ sumf, u16* __restrict__ xb,
           const u16* __restrict__ Wdn, const u16* __restrict__ Wsn,
           const float* __restrict__ b1n,
           u16* __restrict__ y1, u16* __restrict__ y2){
  __shared__ u16 Ab[TM][4*KP];        // 36.9 KB: A(K=256) -> h(panels 0-1) + y(panels 2-3)
  __shared__ float bls[H], b2s[H], lgs[H], lbs[H], b1s[H];
  const int tid = threadIdx.x;
  const int wave = tid>>6, l = tid&63, l15 = l&15, quad = l>>4;
  const int wrow = wave*16, q8 = quad*8;
  const int rowbase = blockIdx.x*TM;
  if (tid < H){ bls[tid] = b1[tid]; b2s[tid] = b2[tid]; lgs[tid] = lng[tid];
                if (DOY12) b1s[tid] = b1n[tid]; }
  else lbs[tid-H] = lnb[tid-H];
  NSTAGE_AF(Ab, aggr + (size_t)rowbase*H, 0)
  NSTAGE_AF(Ab, aggr + (size_t)rowbase*H, 1)
  {
    const u16* xs = xin + (size_t)rowbase*H - 128;   // panels 2,3 map to cols 0,64
    NSTAGE_A(Ab, xs, 2) NSTAGE_A(Ab, xs, 3)
  }
  __syncthreads();                                    // only barrier
  f32x4 acc[8];
#pragma unroll
  for (int t=0;t<8;t++) acc[t] = (f32x4)(0.f);
  GFMFMA(W1g, 0, 4, acc)
  {
    float4 z = make_float4(0.f,0.f,0.f,0.f);
#pragma unroll
    for (int i=0;i<8;i++){
      int o = tid + i*256;
      *(float4*)&aggr[(size_t)rowbase*H + (size_t)o*4] = z;
    }
  }
  // h -> Ab panels 0..1 (wave-private rows; compiler tracks LDS dep)
#pragma unroll
  for (int t=0;t<8;t++){
    int co = t*16 + quad*4;
    int po = (co>>6)*KP + (co&63);
    *(uint2*)&Ab[wrow + l15][po] = pack4(
      siluf_(acc[t][0]+bls[co]),   siluf_(acc[t][1]+bls[co+1]),
      siluf_(acc[t][2]+bls[co+2]), siluf_(acc[t][3]+bls[co+3]));
  }
#pragma unroll
  for (int t=0;t<8;t++) acc[t] = (f32x4)(0.f);
  GFMFMA(W2g, 0, 2, acc)
  const int node = rowbase + wrow + l15;
  const size_t ro = (size_t)node*H;
  float y[8][4]; float s = 0.f, ss = 0.f;
#pragma unroll
  for (int t=0;t<8;t++){
    int co = t*16 + quad*4;
    float4 xv = *(const float4*)&x[ro + co];
    y[t][0] = xv.x + acc[t][0] + b2s[co];
    y[t][1] = xv.y + acc[t][1] + b2s[co+1];
    y[t][2] = xv.z + acc[t][2] + b2s[co+2];
    y[t][3] = xv.w + acc[t][3] + b2s[co+3];
#pragma unroll
    for (int r=0;r<4;r++){ s += y[t][r]; ss += y[t][r]*y[t][r]; }
  }
  s  += __shfl_xor(s, 16);  s  += __shfl_xor(s, 32);
  ss += __shfl_xor(ss, 16); ss += __shfl_xor(ss, 32);
  float mean = s*(1.0f/H);
  float var  = ss*(1.0f/H) - mean*mean;
  float inv  = rsqrtf(var + 1e-5f);
#pragma unroll
  for (int t=0;t<8;t++){
    int co = t*16 + quad*4;
    float4 o;
    o.x = (y[t][0]-mean)*inv*lgs[co]   + lbs[co];
    o.y = (y[t][1]-mean)*inv*lgs[co+1] + lbs[co+1];
    o.z = (y[t][2]-mean)*inv*lgs[co+2] + lbs[co+2];
    o.w = (y[t][3]-mean)*inv*lgs[co+3] + lbs[co+3];
    *(float4*)&x[ro + co] = o;
    if (ADDSUM){
      float4 sf = *(const float4*)&sumf[ro + co];
      sf.x += o.x*(1.0f/3.0f); sf.y += o.y*(1.0f/3.0f);
      sf.z += o.z*(1.0f/3.0f); sf.w += o.w*(1.0f/3.0f);
      *(float4*)&sumf[ro + co] = sf;
      if (!DOY12)   // last layer: emit bf16 of the final mean (atom_features, LINEAR)
        *(uint2*)&y1[ro + co] = pack4(sf.x, sf.y, sf.z, sf.w);
    }
    *(uint2*)&xb[ro + co] = pack4(o.x, o.y, o.z, o.w);
    y[t][0] = o.x; y[t][1] = o.y; y[t][2] = o.z; y[t][3] = o.w;
  }

  if (DOY12){
#pragma unroll
    for (int t=0;t<8;t++){
      int co = t*16 + quad*4;
      int po = (2 + (co>>6))*KP + (co&63);
      *(uint2*)&Ab[wrow + l15][po] = pack4(y[t][0], y[t][1], y[t][2], y[t][3]);
    }
    f32x4 a1[8], a2[8];
#pragma unroll
    for (int t=0;t<8;t++){ a1[t] = (f32x4)(0.f); a2[t] = (f32x4)(0.f); }
    GFMFMA(Wdn, 2, 2, a1)
    GFMFMA(Wsn, 2, 2, a2)
#pragma unroll
    for (int t=0;t<8;t++){
      int co = t*16 + quad*4;
      int pc = permc(co);
      *(uint2*)&y1[ro + pc] = pack4(
        a1[t][0]+b1s[co], a1[t][1]+b1s[co+1], a1[t][2]+b1s[co+2], a1[t][3]+b1s[co+3]);
      *(uint2*)&y2[ro + pc] = pack4(a2[t][0], a2[t][1], a2[t][2], a2[t][3]);
    }
  }
}

// FUSED tail: af -> h1=silu(ro1) -> ae=ro2 (f32 out) -> {h=silu(pn) -> hb,
// g = tanh(ae@gp1+b)@gp_w2+b2 -> gsc}. All W from frag-packed global.
__global__ __launch_bounds__(256, 2)
void k_tail(const u16* __restrict__ afb,
            const u16* __restrict__ Wro1, const float* __restrict__ bro1,
            const u16* __restrict__ Wro2, const float* __restrict__ bro2,
            const u16* __restrict__ Wpn,  const float* __restrict__ bpn,
            const u16* __restrict__ Wgp,  const float* __restrict__ bgp,
            const float* __restrict__ w2, const float* __restrict__ b2g,
            float* __restrict__ out_ae, u16* __restrict__ hb,
            float* __restrict__ g){
  __shared__ u16 Ab[TM][2*KP];
  __shared__ float r1b[H], r2b[H], pnb[H], g1b[H], w2s[H];
  const int tid = threadIdx.x;
  const int wave = tid>>6, l = tid&63, l15 = l&15, quad = l>>4;
  const int wrow = wave*16, q8 = quad*8;
  const int rowbase = blockIdx.x*TM;
  if (tid < H){ r1b[tid]=bro1[tid]; r2b[tid]=bro2[tid]; pnb[tid]=bpn[tid]; g1b[tid]=bgp[tid]; }
  else w2s[tid-H] = w2[tid-H];
  NSTAGE_A(Ab, afb + (size_t)rowbase*H, 0) NSTAGE_A(Ab, afb + (size_t)rowbase*H, 1)
  __syncthreads();                                    // only barrier
  f32x4 acc[8];
#pragma unroll
  for (int t=0;t<8;t++) acc[t] = (f32x4)(0.f);
  GFMFMA(Wro1, 0, 2, acc)
  // h1 = silu(af@ro1 + b) -> Ab (wave-private rows)
#pragma unroll
  for (int t=0;t<8;t++){
    int co = t*16 + quad*4;
    int po = (co>>6)*KP + (co&63);
    *(uint2*)&Ab[wrow + l15][po] = pack4(
      siluf_(acc[t][0]+r1b[co]),   siluf_(acc[t][1]+r1b[co+1]),
      siluf_(acc[t][2]+r1b[co+2]), siluf_(acc[t][3]+r1b[co+3]));
  }
#pragma unroll
  for (int t=0;t<8;t++) acc[t] = (f32x4)(0.f);
  GFMFMA(Wro2, 0, 2, acc)
  const int node = rowbase + wrow + l15;
  const size_t ro = (size_t)node*H;
#pragma unroll
  for (int t=0;t<8;t++){
    int co = t*16 + quad*4;
    float v0 = acc[t][0]+r2b[co],   v1 = acc[t][1]+r2b[co+1];
    float v2 = acc[t][2]+r2b[co+2], v3 = acc[t][3]+r2b[co+3];
    float4 o; o.x=v0; o.y=v1; o.z=v2; o.w=v3;
    *(float4*)&out_ae[ro + co] = o;
    int po = (co>>6)*KP + (co&63);
    *(uint2*)&Ab[wrow + l15][po] = pack4(v0,v1,v2,v3);
  }
#pragma unroll
  for (int t=0;t<8;t++) acc[t] = (f32x4)(0.f);
  GFMFMA(Wpn, 0, 2, acc)
#pragma unroll
  for (int t=0;t<8;t++){
    int co = t*16 + quad*4;
    *(uint2*)&hb[ro + co] = pack4(
      siluf_(acc[t][0]+pnb[co]),   siluf_(acc[t][1]+pnb[co+1]),
      siluf_(acc[t][2]+pnb[co+2]), siluf_(acc[t][3]+pnb[co+3]));
  }
#pragma unroll
  for (int t=0;t<8;t++) acc[t] = (f32x4)(0.f);
  GFMFMA(Wgp, 0, 2, acc)
  float p = 0.f;
#pragma unroll
  for (int t=0;t<8;t++){
    int co = t*16 + quad*4;
#pragma unroll
    for (int r=0;r<4;r++) p = fmaf(tanhf(acc[t][r]+g1b[co+r]), w2s[co+r], p);
  }
  p += __shfl_xor(p, 16); p += __shfl_xor(p, 32);
  if (quad == 0) g[node] = p + b2g[0];
}

// ---------------------------------------------------------------- pooling
__global__ void k_start(const int* __restrict__ batch, int* __restrict__ start){
  int b = threadIdx.x;
  if (b > NB) return;
  if (b == NB){ start[NB] = NN; return; }
  int lo = 0, hi = NN;
  while (lo < hi){ int mid = (lo+hi) >> 1; if (batch[mid] < b) lo = mid+1; else hi = mid; }
  start[b] = lo;
}

__global__ __launch_bounds__(256)
void k_pool(const int* __restrict__ start, const float* __restrict__ g,
            const u16* __restrict__ hb, float* __restrict__ out){
  const int b   = blockIdx.x / PB;
  const int sub = blockIdx.x % PB;
  const int s = start[b], e = start[b+1];
  const int tid = threadIdx.x;
  __shared__ float red[4];
  __shared__ float s_gmax, s_den;
  __shared__ float part[2][H];

  float mx = -1e30f;
  for (int n = s + tid; n < e; n += 256) mx = fmaxf(mx, g[n]);
#pragma unroll
  for (int m=32;m>=1;m>>=1) mx = fmaxf(mx, __shfl_xor(mx, m, 64));
  if ((tid & 63) == 0) red[tid >> 6] = mx;
  __syncthreads();
  if (tid == 0){
    float v = fmaxf(fmaxf(red[0],red[1]), fmaxf(red[2],red[3]));
    s_gmax = (e > s) ? v : 0.0f;
  }
  __syncthreads();
  const float gmax = s_gmax;

  float sum = 0.f;
  for (int n = s + tid; n < e; n += 256) sum += __expf(g[n] - gmax);
#pragma unroll
  for (int m=32;m>=1;m>>=1) sum += __shfl_xor(sum, m, 64);
  if ((tid & 63) == 0) red[tid >> 6] = sum;
  __syncthreads();
  if (tid == 0) s_den = red[0]+red[1]+red[2]+red[3];
  __syncthreads();
  const float den = s_den;
  if (den <= 0.f) return;

  int len = e - s;
  int chunk = (len + PB - 1) / PB;
  int ns = s + sub*chunk;
  int ne = ns + chunk; if (ne > e) ne = e;
  if (ns >= ne) return;

  const int col = tid & 127, rg = tid >> 7;
  float acc = 0.f;
  for (int n = ns + rg; n < ne; n += 2)
    acc = fmaf(__expf(g[n] - gmax), bf2f(hb[(size_t)n*H + col]), acc);
  part[rg][col] = acc;
  __syncthreads();
  if (tid < H){
    float v = part[0][tid] + part[1][tid];
    if (v != 0.f) atomicAdd(&out[b*H + tid], v/den);
  }
}

// ================================================================ host
extern "C" void kernel_launch(void* const* d_in, const int* in_sizes, int n_in,
                              void* d_out, int out_size, void* d_ws, size_t ws_size,
                              hipStream_t stream){
  const int*   Z      = (const int*)  d_in[0];
  const float* pos    = (const float*)d_in[1];
  const int*   batch  = (const int*)  d_in[2];
  const int*   ei     = (const int*)  d_in[3];
  const float* embed  = (const float*)d_in[4];
  const float* widths = (const float*)d_in[5];
  const float* ee_w1  = (const float*)d_in[6];
  const float* ee_b1  = (const float*)d_in[7];
  const float* ee_w2  = (const float*)d_in[8];
  const float* ee_b2  = (const float*)d_in[9];
  const float* msg_w1 = (const float*)d_in[10];
  const float* msg_b1 = (const float*)d_in[11];
  const float* msg_w2 = (const float*)d_in[12];
  const float* msg_b2 = (const float*)d_in[13];
  const float* gate_w = (const float*)d_in[14];
  const float* gate_b = (const float*)d_in[15];
  const float* upd_w1 = (const float*)d_in[16];
  const float* upd_b1 = (const float*)d_in[17];
  const float* upd_w2 = (const float*)d_in[18];
  const float* upd_b2 = (const float*)d_in[19];
  const float* ln_g   = (const float*)d_in[20];
  const float* ln_b   = (const float*)d_in[21];
  const float* gp_w1  = (const float*)d_in[22];
  const float* gp_b1  = (const float*)d_in[23];
  const float* gp_w2  = (const float*)d_in[24];
  const float* gp_b2  = (const float*)d_in[25];
  const float* pn_w   = (const float*)d_in[26];
  const float* pn_b   = (const float*)d_in[27];
  const float* ro_w1  = (const float*)d_in[28];
  const float* ro_b1  = (const float*)d_in[29];
  const float* ro_w2  = (const float*)d_in[30];
  const float* ro_b2  = (const float*)d_in[31];

  const int* srcv = ei;
  const int* dstv = ei + NE;

  // ---- workspace carve (64B-aligned) — ~40 MB total
  char* p0 = (char*)d_ws;
  char* p = p0;
  auto carve = [&](size_t bytes)->char*{ char* q = p; p += (bytes + 63) & ~(size_t)63; return q; };
  float* x     = (float*)carve((size_t)NH*4);
  float* aggr  = (float*)carve((size_t)NH*4);
  float* gsc   = (float*)carve((size_t)NN*4);
  float* exb   = (float*)carve((size_t)NN*4);
  int*   startb  = (int*)carve((size_t)(NB+2)*4);
  int*   estart  = (int*)carve((size_t)(NN+1)*4);
  int*   ecursor = (int*)carve((size_t)NN*4);
  int*   src_s   = (int*)carve((size_t)NE*4);
  int*   dst_s   = (int*)carve((size_t)NE*4);
  u16*   xb      = (u16*)carve((size_t)NH*2);
  u16*   packw   = (u16*)carve((size_t)4*LT2*2);
  u16*   packn   = (u16*)carve((size_t)(NG+65536)*2);
  u16*   nb1     = (u16*)carve((size_t)NH*2);   // y1 during edge phase
  u16*   nb2     = (u16*)carve((size_t)NH*2);   // y2 during edge phase
  u16*   m1tab   = (u16*)carve((size_t)4*TT*H*2);   // 4 MB: m1e(d) tables (permuted)
  u16*   gtab    = (u16*)carve((size_t)4*TT*H*2);   // 4 MB: gate(d) tables (permuted)

  float* out_af  = (float*)d_out;     // running sum of (feat/3) over last-3 layers
  float* out_ae  = out_af + NH;
  float* out_gaf = out_ae + NH;

  // ---- once-per-call prep
  k_pack<<<dim3((LT2+255)/256, 4), 256, 0, stream>>>(ee_w1, ee_w2, msg_w1, msg_w2, gate_w, packw);
  k_packn<<<(NG+65536+255)/256, 256, 0, stream>>>(upd_w1, upd_w2, ro_w1, ro_w2, pn_w, gp_w1, packn);
  k_table<<<dim3(TT/TM, 4), 256, 0, stream>>>(packw, widths, ee_b1, ee_b2, gate_b, m1tab, gtab);
  k_zero_i<<<(NN+255)/256, 256, 0, stream>>>(ecursor, NN);
  k_hist<<<NE/256, 256, 0, stream>>>(dstv, ecursor);
  k_scan<<<1, 1024, 0, stream>>>(ecursor, estart);
  k_scatter<<<NE/256, 256, 0, stream>>>(srcv, dstv, ecursor, src_s, dst_s);
  k_embed<<<NH/256, 256, 0, stream>>>(Z, embed, x, xb);
  k_zero<<<NH/256, 256, 0, stream>>>(out_af, NH);
  k_zero<<<(NB*H+255)/256, 256, 0, stream>>>(out_gaf, NB*H);
  k_zero<<<NH/256, 256, 0, stream>>>(aggr, NH);   // layer 0 only; k_upd re-zeros

  // layer-0 y1/y2 (subsequent layers fused into k_upd)
  k_y12<<<NN/TM, 256, 0, stream>>>(xb, packw + 82944, packw + 99328, msg_b1, nb1, nb2);

  for (int l=0; l<4; l++){
    const u16* pwn = packn + (size_t)l*LN_;
    const u16* pwN = packw + (size_t)(l+1)*LT2;   // next-layer edge pack (for fused y12)
    k_edge<<<NE/EPB, 256, 0, stream>>>(src_s, dst_s, pos, nb1, nb2,
                                       packw + (size_t)l*LT2 + 64512,
                                       m1tab + (size_t)l*TT*H, gtab + (size_t)l*TT*H,
                                       msg_b2 + l*H, aggr);
    if (l == 0)
      k_upd<0,1><<<NN/TM, 256, 0, stream>>>(aggr, xb, pwn, upd_b1 + l*H,
                                            pwn + 32768, upd_b2 + l*H,
                                            ln_g + l*H, ln_b + l*H, x, out_af, xb,
                                            pwN + 82944, pwN + 99328, msg_b1 + (l+1)*H,
                                            nb1, nb2);
    else if (l < 3)
      k_upd<1,1><<<NN/TM, 256, 0, stream>>>(aggr, xb, pwn, upd_b1 + l*H,
                                            pwn + 32768, upd_b2 + l*H,
                                            ln_g + l*H, ln_b + l*H, x, out_af, xb,
                                            pwN + 82944, pwN + 99328, msg_b1 + (l+1)*H,
                                            nb1, nb2);
    else
      k_upd<1,0><<<NN/TM, 256, 0, stream>>>(aggr, xb, pwn, upd_b1 + l*H,
                                            pwn + 32768, upd_b2 + l*H,
                                            ln_g + l*H, ln_b + l*H, x, out_af, xb,
                                            packw, packw, msg_b1,
                                            nb1, nb2);
  }

  // fused tail: nb1 = bf16(atom_features) from last k_upd (linear layout)
  k_tail<<<NN/TM, 256, 0, stream>>>(nb1,
                                    packn + NG,         ro_b1,
                                    packn + NG + 16384, ro_b2,
                                    packn + NG + 32768, pn_b,
                                    packn + NG + 49152, gp_b1, gp_w2, gp_b2,
                                    out_ae, nb2, gsc);
  k_start<<<1, 64, 0, stream>>>(batch, startb);
  k_pool<<<NB*PB, 256, 0, stream>>>(startb, gsc, nb2, out_gaf);
}

// Round 10
// 534.199 us; speedup vs baseline: 1.1999x; 1.1999x over previous
//
#include <hip/hip_runtime.h>

#define NN   16384
#define NE   262144
#define NB   32
#define H    128
#define NH   (NN*H)
#define RBF  50
#define TM   64
#define KC   64
#define KP   72     // node-kernel LDS panel pitch (u16)
#define HBP  136    // edge reduce-buffer pitch (u16): 272 B rows
#define CHW  9216   // edge weight chunk: [128 rows][72 u16] (64 k + 8 pad)
#define LT2  115712 // packed edge weights per layer: 9*9216 + 16384(m1d) + 16384(m1s)
#define LN_  49152  // packed node weights per layer (u16)
#define NG   196608 // offset of global node weights in packn
#define EPB  128    // edges per block (k_edge)
#define WEV  32     // edges per wave  (k_edge)
#define TT   4096   // distance-table resolution
#define TW   256    // interleaved table row width (u16): m1e[128] | gate[128]
#define PB   32     // k_pool blocks per batch

typedef unsigned short u16;
typedef short bf16x8 __attribute__((ext_vector_type(8)));
typedef float f32x4 __attribute__((ext_vector_type(4)));
typedef float f32x16 __attribute__((ext_vector_type(16)));
typedef unsigned u32x2 __attribute__((ext_vector_type(2)));

#if defined(__has_builtin)
#if __has_builtin(__builtin_amdgcn_cvt_pk_bf16_f32)
#define HAS_PK_BF16 1
#endif
#if __has_builtin(__builtin_amdgcn_permlane32_swap)
#define HAS_PLSWAP 1
#endif
#endif

__device__ __forceinline__ float sigmoidf_(float v){ return 1.0f/(1.0f + __expf(-v)); }
__device__ __forceinline__ float siluf_(float v){ return v * sigmoidf_(v); }
__device__ __forceinline__ u16 f2bf(float f){
  unsigned u = __float_as_uint(f);
  return (u16)((u + 0x7FFFu + ((u>>16)&1u)) >> 16);
}
__device__ __forceinline__ float bf2f(u16 v){ return __uint_as_float(((unsigned)v)<<16); }
__device__ __forceinline__ unsigned pk2(float a, float b){
#ifdef HAS_PK_BF16
  typedef __bf16 v2bf __attribute__((ext_vector_type(2)));
  v2bf v = __builtin_amdgcn_cvt_pk_bf16_f32(a, b);
  return __builtin_bit_cast(unsigned, v);
#else
  return (unsigned)f2bf(a) | ((unsigned)f2bf(b)<<16);
#endif
}
__device__ __forceinline__ uint2 pack4(float a, float b, float c, float d){
  uint2 r; r.x = pk2(a,b); r.y = pk2(c,d); return r;
}
__device__ __forceinline__ float blo(unsigned u){ return bf2f((u16)(u & 0xffffu)); }
__device__ __forceinline__ float bhi(unsigned u){ return bf2f((u16)(u >> 16)); }

// fragment-order permutation: perm[hi*64+16t+4u+j] = orig[32t+4hi+8u+j]
__device__ __forceinline__ int permc(int c){
  return ((c>>2)&1)*64 + ((c>>5)&3)*16 + ((c>>3)&3)*4;
}

// ---- permlane32_swap: exchange hi-half of 'a' with lo-half of 'b' across lane 32 boundary
__device__ __forceinline__ void plswap(unsigned a, unsigned b, unsigned &x, unsigned &y){
#ifdef HAS_PLSWAP
  u32x2 q = __builtin_amdgcn_permlane32_swap(a, b, false, false);
  x = q.x; y = q.y;          // x = (aL,bL), y = (aH,bH)
#else
  int l_ = (int)(threadIdx.x & 63);
  unsigned as_ = __shfl(a, l_^32);
  unsigned bs_ = __shfl(b, l_^32);
  x = (l_ < 32) ? a : bs_;
  y = (l_ < 32) ? as_ : b;
#endif
}

// ---- pack 16 f32 (one 32x32 C tile per lane) into two B-frags (steps 2t, 2t+1)
__device__ __forceinline__ void pack_frags(const float* v, uint4& f0, uint4& f1){
  unsigned P0 = pk2(v[0],v[1]),   P1 = pk2(v[2],v[3]);
  unsigned P2 = pk2(v[4],v[5]),   P3 = pk2(v[6],v[7]);
  unsigned P4 = pk2(v[8],v[9]),   P5 = pk2(v[10],v[11]);
  unsigned P6 = pk2(v[12],v[13]), P7 = pk2(v[14],v[15]);
  unsigned x0,y0,x1,y1,x2,y2,x3,y3;
  plswap(P0,P2,x0,y0); plswap(P1,P3,x1,y1);
  plswap(P4,P6,x2,y2); plswap(P5,P7,x3,y3);
  f0.x=x0; f0.y=x1; f0.z=y0; f0.w=y1;
  f1.x=x2; f1.y=x3; f1.z=y2; f1.w=y3;
}

// ---- global->LDS direct staging (width 16 / width 4)
__device__ __forceinline__ void gll16(const u16* g, u16* l){
  __builtin_amdgcn_global_load_lds((const __attribute__((address_space(1))) void*)g,
                                   (__attribute__((address_space(3))) void*)l, 16, 0, 0);
}
__device__ __forceinline__ void gll4(const u16* g, u16* l){
  __builtin_amdgcn_global_load_lds((const __attribute__((address_space(1))) void*)g,
                                   (__attribute__((address_space(3))) void*)l, 4, 0, 0);
}

// ---------------------------------------------------------------- utility
__global__ void k_zero(float* __restrict__ p, int n){
  int i = blockIdx.x*256 + threadIdx.x; if (i < n) p[i] = 0.f;
}
__global__ void k_zero_i(int* __restrict__ p, int n){
  int i = blockIdx.x*256 + threadIdx.x; if (i < n) p[i] = 0;
}
__global__ void k_embed(const int* __restrict__ z, const float* __restrict__ emb,
                        float* __restrict__ x, u16* __restrict__ xb){
  int i = blockIdx.x*256 + threadIdx.x;
  int n = i >> 7, h = i & 127;
  float v = emb[z[n]*H + h];
  x[i] = v; xb[i] = f2bf(v);
}

// ---------------------------------------------------------------- weight packing
// Edge layout per layer: chunks c=0..8 of [128][72] (64 valid k):
// 0:ee1 1,2:ee2 3,4:m1e 5,6:gate 7,8:msg2 ; then m1d dense @82944, m1s dense @99328.
__global__ void k_pack(const float* __restrict__ ee_w1, const float* __restrict__ ee_w2,
                       const float* __restrict__ msg_w1, const float* __restrict__ msg_w2,
                       const float* __restrict__ gate_w, u16* __restrict__ out){
  int idx = blockIdx.x*256 + threadIdx.x;
  int l = blockIdx.y;
  if (idx >= LT2) return;
  u16* o = out + (size_t)l*LT2;
  float v = 0.f;
  if (idx < 82944){
    int c = idx / CHW, r = idx % CHW, row = r / 72, col = r % 72;
    if (col < 64){
      if (c == 0)      v = (col < RBF) ? ee_w1[(size_t)l*RBF*H + col*H + row] : 0.f;
      else if (c <= 2) v = ee_w2 [(size_t)l*H*H + (64*(c-1)+col)*H + row];
      else if (c <= 4) v = msg_w1[(size_t)l*3*H*H + (256 + 64*(c-3)+col)*H + row];
      else if (c <= 6) v = gate_w[(size_t)l*H*H + (64*(c-5)+col)*H + row];
      else             v = msg_w2[(size_t)l*H*H + (64*(c-7)+col)*H + row];
    }
  } else if (idx < 99328){
    int j = idx - 82944; int row = j >> 7, k = j & 127;
    v = msg_w1[(size_t)l*3*H*H + k*H + row];
  } else {
    int j = idx - 99328; int row = j >> 7, k = j & 127;
    v = msg_w1[(size_t)l*3*H*H + (128+k)*H + row];
  }
  o[idx] = f2bf(v);
}

__global__ void k_packn(const float* __restrict__ upd_w1, const float* __restrict__ upd_w2,
                        const float* __restrict__ ro_w1, const float* __restrict__ ro_w2,
                        const float* __restrict__ pn_w, const float* __restrict__ gp_w1,
                        u16* __restrict__ out){
  int idx = blockIdx.x*256 + threadIdx.x;
  if (idx >= NG + 65536) return;
  float v;
  if (idx < NG){
    int l = idx / LN_, j = idx % LN_;
    if (j < 32768){ int c = j>>8, k = j&255; v = upd_w1[(size_t)l*256*H + k*H + c]; }
    else { int j2 = j-32768; int c = j2>>7, k = j2&127; v = upd_w2[(size_t)l*H*H + k*H + c]; }
  } else {
    int j = idx - NG; int m = j >> 14; int j2 = j & 16383;
    int c = j2>>7, k = j2&127;
    const float* W = (m==0) ? ro_w1 : (m==1) ? ro_w2 : (m==2) ? pn_w : gp_w1;
    v = W[k*H + c];
  }
  out[idx] = f2bf(v);
}

// ---------------------------------------------------------------- edge sort by dst
__global__ void k_hist(const int* __restrict__ dstv, int* __restrict__ cnt){
  int e = blockIdx.x*256 + threadIdx.x;
  if (e < NE) atomicAdd(&cnt[dstv[e]], 1);
}
__global__ __launch_bounds__(1024)
void k_scan(int* __restrict__ cnt, int* __restrict__ start){
  __shared__ int ps[1024];
  int tid = threadIdx.x;
  int base = tid*16;
  int loc[16]; int s = 0;
#pragma unroll
  for (int i=0;i<16;i++){ loc[i] = s; s += cnt[base+i]; }
  ps[tid] = s; __syncthreads();
  for (int off=1; off<1024; off<<=1){
    int v = (tid>=off) ? ps[tid-off] : 0;
    __syncthreads();
    ps[tid] += v;
    __syncthreads();
  }
  int pre = (tid>0) ? ps[tid-1] : 0;
#pragma unroll
  for (int i=0;i<16;i++){ int v = pre + loc[i]; start[base+i] = v; cnt[base+i] = v; }
  if (tid == 0) start[NN] = NE;
}
__global__ void k_scatter(const int* __restrict__ srcv, const int* __restrict__ dstv,
                          int* __restrict__ cursor, int* __restrict__ src_s,
                          int* __restrict__ dst_s){
  int e = blockIdx.x*256 + threadIdx.x;
  if (e >= NE) return;
  int d = dstv[e];
  int p = atomicAdd(&cursor[d], 1);
  src_s[p] = srcv[e]; dst_s[p] = d;
}

// ---------------------------------------------------------------- distance tables
// m1e(d), gate(d) tabulated at TT points over [0,5], INTERLEAVED per row:
// tab[i][0..127]=m1e (permuted frag order), tab[i][128..255]=gate (permuted).
#define TMFMA(CHP, AOFF, ACC) \
  _Pragma("unroll") \
  for (int ks_=0; ks_<64; ks_+=32){ \
    bf16x8 bf_ = *(const bf16x8*)&Ab[wrow + l15][(AOFF) + ks_ + q8]; \
    _Pragma("unroll") \
    for (int t_=0;t_<8;t_++){ \
      bf16x8 wf_ = *(const bf16x8*)&(CHP)[(t_*16 + l15)*72 + ks_ + q8]; \
      ACC[t_] = __builtin_amdgcn_mfma_f32_16x16x32_bf16(wf_, bf_, ACC[t_], 0, 0, 0); \
    } \
  }

__global__ __launch_bounds__(256)
void k_table(const u16* __restrict__ packw, const float* __restrict__ widths,
             const float* __restrict__ ee_b1, const float* __restrict__ ee_b2,
             const float* __restrict__ gate_b,
             u16* __restrict__ tab){
  __shared__ u16 CH[7][CHW];        // 129 KB: chunks 0..6 (ee1, ee2x2, m1ex2, gatex2)
  __shared__ u16 Ab[TM][2*KP];      // 18.4 KB
  __shared__ float b1s[H], b2s[H], bgs[H];
  const int tid = threadIdx.x;
  const int wave = tid>>6, l = tid&63, l15 = l&15, quad = l>>4;
  const int wrow = wave*16, q8 = quad*8;
  const int lyr = blockIdx.y;
  const int rowbase = blockIdx.x*TM;
  const u16* pw = packw + (size_t)lyr*LT2;
  if (tid < H){ b1s[tid] = ee_b1[lyr*H+tid]; b2s[tid] = ee_b2[lyr*H+tid];
                bgs[tid] = gate_b[lyr*H+tid]; }
#pragma unroll
  for (int c=0;c<7;c++){
    const u16* gs = pw + (size_t)c*CHW;
    u16* ls = &CH[c][0];
#pragma unroll
    for (int i=0;i<4;i++) gll16(gs + (i*256+tid)*8, ls + (i*256+tid)*8);
#pragma unroll
    for (int i=0;i<2;i++) gll4(gs + 8192 + (i*256+tid)*2, ls + 8192 + (i*256+tid)*2);
  }
  // rbf rows (64 samples x 64 cols; cols >= RBF zero)
  {
    int r = tid>>2, k0 = (tid&3)*16;
    float d = 5.0f*(float)(rowbase + r)/(float)(TT-1);
    float cut = (d < 5.0f) ? 0.5f*(__cosf(0.62831853f*d)+1.0f) : 0.0f;
    unsigned vv[8];
#pragma unroll
    for (int j=0;j<8;j++){
      int ka = k0+2*j, kb = ka+1;
      float wa = widths[ka < RBF ? ka : 0], wb = widths[kb < RBF ? kb : 0];
      float ta = d - 0.10204082f*(float)ka;
      float tb = d - 0.10204082f*(float)kb;
      float va = (ka<RBF)? __expf(-(1.0f/(2.0f*wa*wa))*ta*ta)*cut : 0.f;
      float vb = (kb<RBF)? __expf(-(1.0f/(2.0f*wb*wb))*tb*tb)*cut : 0.f;
      vv[j] = pk2(va,vb);
    }
    uint4 u0; u0.x=vv[0]; u0.y=vv[1]; u0.z=vv[2]; u0.w=vv[3];
    uint4 u1; u1.x=vv[4]; u1.y=vv[5]; u1.z=vv[6]; u1.w=vv[7];
    *(uint4*)&Ab[r][k0]   = u0;
    *(uint4*)&Ab[r][k0+8] = u1;
  }
  __syncthreads();
  f32x4 acc[8];
  // ee hidden = silu(rbf @ ee_w1 + b1)  (K=64, chunk0)
#pragma unroll
  for (int t=0;t<8;t++) acc[t] = (f32x4)(0.f);
  TMFMA(CH[0], 0, acc)
  const int s = rowbase + wrow + l15;
#pragma unroll
  for (int t=0;t<8;t++){
    int co = t*16 + quad*4;
    int po = (co>>6)*KP + (co&63);
    *(uint2*)&Ab[wrow + l15][po] = pack4(
      siluf_(acc[t][0]+b1s[co]),   siluf_(acc[t][1]+b1s[co+1]),
      siluf_(acc[t][2]+b1s[co+2]), siluf_(acc[t][3]+b1s[co+3]));
  }
  // ee = h @ ee_w2 + b2 (K=128, chunks 1,2)
#pragma unroll
  for (int t=0;t<8;t++) acc[t] = (f32x4)(0.f);
  TMFMA(CH[1], 0, acc)
  TMFMA(CH[2], KP, acc)
#pragma unroll
  for (int t=0;t<8;t++){
    int co = t*16 + quad*4;
    int po = (co>>6)*KP + (co&63);
    *(uint2*)&Ab[wrow + l15][po] = pack4(
      acc[t][0]+b2s[co], acc[t][1]+b2s[co+1], acc[t][2]+b2s[co+2], acc[t][3]+b2s[co+3]);
  }
  // m1e = ee @ msg_w1e (chunks 3,4) -> tab[s][0..127] (permuted)
#pragma unroll
  for (int t=0;t<8;t++) acc[t] = (f32x4)(0.f);
  TMFMA(CH[3], 0, acc)
  TMFMA(CH[4], KP, acc)
#pragma unroll
  for (int t=0;t<8;t++){
    int co = t*16 + quad*4;
    *(uint2*)&tab[((size_t)lyr*TT + s)*TW + permc(co)] =
      pack4(acc[t][0], acc[t][1], acc[t][2], acc[t][3]);
  }
  // gate = sigmoid(ee @ gate_w + b_g) (chunks 5,6) -> tab[s][128..255] (permuted)
#pragma unroll
  for (int t=0;t<8;t++) acc[t] = (f32x4)(0.f);
  TMFMA(CH[5], 0, acc)
  TMFMA(CH[6], KP, acc)
#pragma unroll
  for (int t=0;t<8;t++){
    int co = t*16 + quad*4;
    *(uint2*)&tab[((size_t)lyr*TT + s)*TW + 128 + permc(co)] = pack4(
      sigmoidf_(acc[t][0]+bgs[co]),   sigmoidf_(acc[t][1]+bgs[co+1]),
      sigmoidf_(acc[t][2]+bgs[co+2]), sigmoidf_(acc[t][3]+bgs[co+3]));
  }
}

// ---------------------------------------------------------------- FUSED edge pipeline
// R18 = R15 (verified 64.5us) + interleaved m1/gate table. Table-driven edges,
// permuted gathers (8x uint4 per half-row), Sb aliased onto weight buffer ->
// 37.4 KB LDS, launch_bounds(256,3).

#define GSTAGE(cidx, dbuf) { \
  const u16* gs_ = pw + (size_t)(cidx)*CHW; \
  u16* ls_ = &UN[(dbuf)*CHW]; \
  _Pragma("unroll") \
  for (int i_=0;i_<4;i_++) \
    gll16(gs_ + (i_*256 + tid)*8, ls_ + (i_*256 + tid)*8); \
  _Pragma("unroll") \
  for (int i_=0;i_<2;i_++) \
    gll4(gs_ + 8192 + (i_*256 + tid)*2, ls_ + 8192 + (i_*256 + tid)*2); \
}

#define ECHUNK32(WB, FR, ACC) \
  _Pragma("unroll") \
  for (int s_=0; s_<4; s_++){ \
    bf16x8 bf_ = __builtin_bit_cast(bf16x8, (FR)[s_]); \
    _Pragma("unroll") \
    for (int t_=0;t_<4;t_++){ \
      bf16x8 wf_ = *(const bf16x8*)&(WB)[(t_*32 + l31)*72 + s_*16 + hi8]; \
      ACC[t_] = __builtin_amdgcn_mfma_f32_32x32x16_bf16(wf_, bf_, ACC[t_], 0, 0, 0); \
    } \
  }

#define ZACC(A) { _Pragma("unroll") for (int z_=0;z_<4;z_++) A[z_] = (f32x16)(0.f); }

#define SEL2(V, UF) (((UF)&1) ? make_uint2((V).z,(V).w) : make_uint2((V).x,(V).y))

#define DWEL(r) (((r)&3)==0 ? dw[(r)>>2].x : ((r)&3)==1 ? dw[(r)>>2].y : \
                 ((r)&3)==2 ? dw[(r)>>2].z : dw[(r)>>2].w)

__global__ __launch_bounds__(256, 3)
void k_edge(const int* __restrict__ src_s, const int* __restrict__ dst_s,
            const float* __restrict__ pos,
            const u16* __restrict__ y1b, const u16* __restrict__ y2b,
            const u16* __restrict__ pw,        // msg2 chunk pair (packw + l*LT2 + 7*CHW)
            const u16* __restrict__ tab,       // interleaved m1/gate table (this layer)
            const float* __restrict__ b_m2, float* __restrict__ aggr){
  __shared__ __align__(16) u16 UN[2*CHW];   // 36.9 KB: msg2 weights, then reduce staging
  __shared__ float BM[H];
  const int tid = threadIdx.x;
  const int wave = tid>>6, l = tid&63, l31 = l&31, hi = l>>5, hi8 = hi*8;
  const int ebase = blockIdx.x*EPB + wave*WEV;
  const int eid   = ebase + l31;
  if (tid < H) BM[tid] = b_m2[tid];

  const int esrc = src_s[eid], edst = dst_s[eid];
  float dx = pos[3*edst]   - pos[3*esrc];
  float dy = pos[3*edst+1] - pos[3*esrc+1];
  float dz = pos[3*edst+2] - pos[3*esrc+2];
  float dist = sqrtf(dx*dx + dy*dy + dz*dz);
  float uu = fminf(dist, 5.0f) * ((float)(TT-1)/5.0f);
  int i0 = (int)uu; if (i0 > TT-2) i0 = TT-2;
  float w = uu - (float)i0;

  // permuted-layout gathers: half-rows as contiguous uint4 runs
  const u16* yp1 = y1b + (size_t)edst*H + hi*64;
  const u16* yp2 = y2b + (size_t)esrc*H + hi*64;
  const u16* tp  = tab + (size_t)i0*TW + hi*64;
  uint4 Y1[8], Y2[8], M0[8], M1[8];
#pragma unroll
  for (int i=0;i<8;i++){
    Y1[i] = *(const uint4*)&yp1[i*8];
    Y2[i] = *(const uint4*)&yp2[i*8];
    M0[i] = *(const uint4*)&tp[i*8];
    M1[i] = *(const uint4*)&tp[TW + i*8];
  }

  GSTAGE(0,0)
  GSTAGE(1,1)

  // msg hidden = silu(lerp(m1e) + y1 + y2) -> B-frags
  uint4 fmh[8];
#pragma unroll
  for (int tf=0;tf<4;tf++){
    float v_[16];
#pragma unroll
    for (int uf=0;uf<4;uf++){
      int iv = 2*tf + (uf>>1);
      uint2 a1 = SEL2(Y1[iv],uf), a2 = SEL2(Y2[iv],uf);
      uint2 m0 = SEL2(M0[iv],uf), m1 = SEL2(M1[iv],uf);
      float p0 = blo(m0.x), p1 = bhi(m0.x), p2 = blo(m0.y), p3 = bhi(m0.y);
      float q0 = blo(m1.x), q1 = bhi(m1.x), q2 = blo(m1.y), q3 = bhi(m1.y);
      v_[4*uf+0] = siluf_(fmaf(w, q0-p0, p0) + blo(a1.x) + blo(a2.x));
      v_[4*uf+1] = siluf_(fmaf(w, q1-p1, p1) + bhi(a1.x) + bhi(a2.x));
      v_[4*uf+2] = siluf_(fmaf(w, q2-p2, p2) + blo(a1.y) + blo(a2.y));
      v_[4*uf+3] = siluf_(fmaf(w, q3-p3, p3) + bhi(a1.y) + bhi(a2.y));
    }
    pack_frags(v_, fmh[2*tf], fmh[2*tf+1]);
  }

  __syncthreads();                     // msg2 chunks staged; BM ready

  // gate rows (adjacent to m1 rows in the interleaved table)
  uint4 G0[8], G1[8];
#pragma unroll
  for (int i=0;i<8;i++){
    G0[i] = *(const uint4*)&tp[128 + i*8];
    G1[i] = *(const uint4*)&tp[TW + 128 + i*8];
  }

  f32x16 acc[4];
  ZACC(acc)
  ECHUNK32((&UN[0]),   fmh,   acc)     // msg2 k0-63
  ECHUNK32((&UN[CHW]), fmh+4, acc)     // msg2 k64-127

  __syncthreads();                     // all waves done reading UN -> reuse as Sb
  u16* Sb = &UN[wave*(WEV*HBP)];       // 32 rows x 136 u16 per wave

  // gated message -> Sb (bf16 pairs)
#pragma unroll
  for (int tf=0;tf<4;tf++){
#pragma unroll
    for (int uf=0;uf<4;uf++){
      int iv = 2*tf + (uf>>1);
      int co = 32*tf + 4*hi + 8*uf;
      float4 bm = *(const float4*)&BM[co];
      uint2 a0 = SEL2(G0[iv],uf), a1 = SEL2(G1[iv],uf);
      float g0 = fmaf(w, blo(a1.x)-blo(a0.x), blo(a0.x));
      float g1 = fmaf(w, bhi(a1.x)-bhi(a0.x), bhi(a0.x));
      float g2 = fmaf(w, blo(a1.y)-blo(a0.y), blo(a0.y));
      float g3 = fmaf(w, bhi(a1.y)-bhi(a0.y), bhi(a0.y));
      float m0 = (acc[tf][4*uf+0]+bm.x)*g0;
      float m1 = (acc[tf][4*uf+1]+bm.y)*g1;
      float m2 = (acc[tf][4*uf+2]+bm.z)*g2;
      float m3 = (acc[tf][4*uf+3]+bm.w)*g3;
      *(uint2*)&Sb[l31*HBP + co] = pack4(m0, m1, m2, m3);
    }
  }

  // ---- wave-local segmented reduce (dst-sorted): 2 cols/lane over 32 rows
  {
    int4 dw[8];
#pragma unroll
    for (int i=0;i<8;i++) dw[i] = *(const int4*)&dst_s[ebase + 4*i];
    int c0 = l*2;
    float a0 = 0.f, a1 = 0.f;
    int cur = dw[0].x;
#pragma unroll
    for (int r=0;r<32;r++){
      int d = DWEL(r);
      if (d != cur){
        atomicAdd(&aggr[(size_t)cur*H + c0],     a0);
        atomicAdd(&aggr[(size_t)cur*H + c0 + 1], a1);
        a0 = 0.f; a1 = 0.f; cur = d;
      }
      unsigned pv = *(const unsigned*)&Sb[r*HBP + c0];
      a0 += blo(pv); a1 += bhi(pv);
    }
    atomicAdd(&aggr[(size_t)cur*H + c0],     a0);
    atomicAdd(&aggr[(size_t)cur*H + c0 + 1], a1);
  }
}

// ---------------------------------------------------------------- node MFMA kernels
// R13 design (verified): fully-fused node phase, single-shot LDS staging,
// wave-private Ab re-fragmentation between chained GEMMs, 1-3 barriers.

#define NMFMA(AB, WB, NP, ACC) \
  _Pragma("unroll") \
  for (int kk_=0; kk_<(NP)*64; kk_+=32){ \
    int po_ = (kk_>>6)*KP + (kk_&63); \
    bf16x8 bf_ = *(const bf16x8*)&AB[wrow + l15][po_ + q8]; \
    _Pragma("unroll") \
    for (int t_=0;t_<8;t_++){ \
      bf16x8 wf_ = *(const bf16x8*)&WB[t_*16 + l15][po_ + q8]; \
      ACC[t_] = __builtin_amdgcn_mfma_f32_16x16x32_bf16(wf_, bf_, ACC[t_], 0, 0, 0); \
    } \
  }

#define NMFMA2(AB, AOFF, WB_, WOFF, ACC) \
  _Pragma("unroll") \
  for (int kk_=0; kk_<64; kk_+=32){ \
    bf16x8 bf_ = *(const bf16x8*)&AB[wrow + l15][(AOFF) + kk_ + q8]; \
    _Pragma("unroll") \
    for (int t_=0;t_<8;t_++){ \
      bf16x8 wf_ = *(const bf16x8*)&WB_[t_*16 + l15][(WOFF) + kk_ + q8]; \
      ACC[t_] = __builtin_amdgcn_mfma_f32_16x16x32_bf16(wf_, bf_, ACC[t_], 0, 0, 0); \
    } \
  }

#define NSTAGE_W2(WB_, GSRC, KPAD, SP, DP) \
  _Pragma("unroll") \
  for (int i_=0;i_<4;i_++){ \
    int o_ = tid + i_*256; int c_ = o_>>3, ko_ = (o_&7)*8; \
    *(uint4*)&WB_[c_][(DP)*KP + ko_] = *(const uint4*)((GSRC) + (size_t)c_*(KPAD) + (SP)*64 + ko_); \
  }
#define NSTAGE_W(WB, GSRC, KPAD, P) NSTAGE_W2(WB, GSRC, KPAD, P, P)

#define NSTAGE_A(AB, GSRC, P) \
  _Pragma("unroll") \
  for (int i_=0;i_<2;i_++){ \
    int o_ = tid*2 + i_; int r_ = o_>>3, ko_ = (o_&7)*8; \
    *(uint4*)&AB[r_][(P)*KP + ko_] = *(const uint4*)((GSRC) + (size_t)r_*H + (P)*64 + ko_); \
  }

#define NSTAGE_AF(AB, GSRC, P) \
  _Pragma("unroll") \
  for (int i_=0;i_<2;i_++){ \
    int o_ = tid*2 + i_; int r_ = o_>>3, ko_ = (o_&7)*8; \
    const float* rp_ = (GSRC) + (size_t)r_*H + (P)*64 + ko_; \
    float4 f0_ = *(const float4*)rp_; \
    float4 f1_ = *(const float4*)(rp_ + 4); \
    uint4 pk_; \
    pk_.x = pk2(f0_.x, f0_.y); pk_.y = pk2(f0_.z, f0_.w); \
    pk_.z = pk2(f1_.x, f1_.y); pk_.w = pk2(f1_.z, f1_.w); \
    *(uint4*)&AB[r_][(P)*KP + ko_] = pk_; \
  }

// standalone y1 = x@W1d + b_m1 ; y2 = x@W1s  (layer 0 only) [permuted y output]
__global__ __launch_bounds__(256)
void k_y12(const u16* __restrict__ xb, const u16* __restrict__ Wd,
           const u16* __restrict__ Ws, const float* __restrict__ b1,
           u16* __restrict__ y1, u16* __restrict__ y2){
  __shared__ u16 Ab[TM][2*KP];
  __shared__ u16 W1[H][2*KP];
  __shared__ u16 W2[H][2*KP];
  __shared__ float bls[H];
  const int tid = threadIdx.x;
  const int wave = tid>>6, l = tid&63, l15 = l&15, quad = l>>4;
  const int wrow = wave*16, q8 = quad*8;
  const int rowbase = blockIdx.x*TM;
  if (tid < H) bls[tid] = b1[tid];
  NSTAGE_W(W1, Wd, 128, 0) NSTAGE_W(W1, Wd, 128, 1)
  NSTAGE_W(W2, Ws, 128, 0) NSTAGE_W(W2, Ws, 128, 1)
  NSTAGE_A(Ab, xb + (size_t)rowbase*H, 0) NSTAGE_A(Ab, xb + (size_t)rowbase*H, 1)
  __syncthreads();
  f32x4 a1[8], a2[8];
#pragma unroll
  for (int t=0;t<8;t++){ a1[t] = (f32x4)(0.f); a2[t] = (f32x4)(0.f); }
  NMFMA(Ab, W1, 2, a1)
  NMFMA(Ab, W2, 2, a2)
  const int node = rowbase + wrow + l15;
#pragma unroll
  for (int t=0;t<8;t++){
    int co = t*16 + quad*4;
    int pc = permc(co);
    *(uint2*)&y1[(size_t)node*H + pc] = pack4(
      a1[t][0]+bls[co], a1[t][1]+bls[co+1], a1[t][2]+bls[co+2], a1[t][3]+bls[co+3]);
    *(uint2*)&y2[(size_t)node*H + pc] = pack4(
      a2[t][0], a2[t][1], a2[t][2], a2[t][3]);
  }
}

// FUSED per-layer node kernel: upd1 (K=256) -> silu -> upd2 -> residual+LN
// (-> ADDSUM sumf/3, last layer emits bf16 mean) -> optional next-layer y1/y2
// (y1/y2 in permuted fragment order for k_edge).
template<int ADDSUM, int DOY12>
__global__ __launch_bounds__(256)
void k_upd(float* __restrict__ aggr, const u16* __restrict__ xin,
           const u16* __restrict__ W1p, const float* __restrict__ b1,
           const u16* __restrict__ W2p, const float* __restrict__ b2,
           const float* __restrict__ lng, const float* __restrict__ lnb,
           float* __restrict__ x, float* __restrict__ sumf, u16* __restrict__ xb,
           const u16* __restrict__ Wdn, const u16* __restrict__ Wsn,
           const float* __restrict__ b1n,
           u16* __restrict__ y1, u16* __restrict__ y2){
  __shared__ u16 Ab[TM][4*KP];        // 36.9 KB: A(K=256) -> h(panels 0-1) + y(panels 2-3)
  __shared__ u16 WB[3][H][2*KP];      // 110.6 KB
  __shared__ float bls[H], b2s[H], lgs[H], lbs[H], b1s[H];
  const int tid = threadIdx.x;
  const int wave = tid>>6, l = tid&63, l15 = l&15, quad = l>>4;
  const int wrow = wave*16, q8 = quad*8;
  const int rowbase = blockIdx.x*TM;
  if (tid < H){ bls[tid] = b1[tid]; b2s[tid] = b2[tid]; lgs[tid] = lng[tid];
                if (DOY12) b1s[tid] = b1n[tid]; }
  else lbs[tid-H] = lnb[tid-H];
  NSTAGE_W2(WB[0], W1p, 256, 0, 0) NSTAGE_W2(WB[0], W1p, 256, 1, 1)
  NSTAGE_W2(WB[1], W1p, 256, 2, 0) NSTAGE_W2(WB[1], W1p, 256, 3, 1)
  NSTAGE_W2(WB[2], W2p, 128, 0, 0) NSTAGE_W2(WB[2], W2p, 128, 1, 1)
  NSTAGE_AF(Ab, aggr + (size_t)rowbase*H, 0)
  NSTAGE_AF(Ab, aggr + (size_t)rowbase*H, 1)
  {
    const u16* xs = xin + (size_t)rowbase*H - 128;   // panels 2,3 map to cols 0,64
    NSTAGE_A(Ab, xs, 2) NSTAGE_A(Ab, xs, 3)
  }
  __syncthreads();                                    // B1
  f32x4 acc[8];
#pragma unroll
  for (int t=0;t<8;t++) acc[t] = (f32x4)(0.f);
  NMFMA2(Ab, 0,    WB[0], 0,  acc)
  NMFMA2(Ab, KP,   WB[0], KP, acc)
  NMFMA2(Ab, 2*KP, WB[1], 0,  acc)
  NMFMA2(Ab, 3*KP, WB[1], KP, acc)
  {
    float4 z = make_float4(0.f,0.f,0.f,0.f);
#pragma unroll
    for (int i=0;i<8;i++){
      int o = tid + i*256;
      *(float4*)&aggr[(size_t)rowbase*H + (size_t)o*4] = z;
    }
  }
#pragma unroll
  for (int t=0;t<8;t++){
    int co = t*16 + quad*4;
    int po = (co>>6)*KP + (co&63);
    *(uint2*)&Ab[wrow + l15][po] = pack4(
      siluf_(acc[t][0]+bls[co]),   siluf_(acc[t][1]+bls[co+1]),
      siluf_(acc[t][2]+bls[co+2]), siluf_(acc[t][3]+bls[co+3]));
  }
  __syncthreads();                                    // B2: WB[0..1] free, h visible
  if (DOY12){
    NSTAGE_W2(WB[0], Wdn, 128, 0, 0) NSTAGE_W2(WB[0], Wdn, 128, 1, 1)
    NSTAGE_W2(WB[1], Wsn, 128, 0, 0) NSTAGE_W2(WB[1], Wsn, 128, 1, 1)
  }
#pragma unroll
  for (int t=0;t<8;t++) acc[t] = (f32x4)(0.f);
  NMFMA2(Ab, 0,  WB[2], 0,  acc)
  NMFMA2(Ab, KP, WB[2], KP, acc)
  const int node = rowbase + wrow + l15;
  const size_t ro = (size_t)node*H;
  float y[8][4]; float s = 0.f, ss = 0.f;
#pragma unroll
  for (int t=0;t<8;t++){
    int co = t*16 + quad*4;
    float4 xv = *(const float4*)&x[ro + co];
    y[t][0] = xv.x + acc[t][0] + b2s[co];
    y[t][1] = xv.y + acc[t][1] + b2s[co+1];
    y[t][2] = xv.z + acc[t][2] + b2s[co+2];
    y[t][3] = xv.w + acc[t][3] + b2s[co+3];
#pragma unroll
    for (int r=0;r<4;r++){ s += y[t][r]; ss += y[t][r]*y[t][r]; }
  }
  s  += __shfl_xor(s, 16);  s  += __shfl_xor(s, 32);
  ss += __shfl_xor(ss, 16); ss += __shfl_xor(ss, 32);
  float mean = s*(1.0f/H);
  float var  = ss*(1.0f/H) - mean*mean;
  float inv  = rsqrtf(var + 1e-5f);
#pragma unroll
  for (int t=0;t<8;t++){
    int co = t*16 + quad*4;
    float4 o;
    o.x = (y[t][0]-mean)*inv*lgs[co]   + lbs[co];
    o.y = (y[t][1]-mean)*inv*lgs[co+1] + lbs[co+1];
    o.z = (y[t][2]-mean)*inv*lgs[co+2] + lbs[co+2];
    o.w = (y[t][3]-mean)*inv*lgs[co+3] + lbs[co+3];
    *(float4*)&x[ro + co] = o;
    if (ADDSUM){
      float4 sf = *(const float4*)&sumf[ro + co];
      sf.x += o.x*(1.0f/3.0f); sf.y += o.y*(1.0f/3.0f);
      sf.z += o.z*(1.0f/3.0f); sf.w += o.w*(1.0f/3.0f);
      *(float4*)&sumf[ro + co] = sf;
      if (!DOY12)   // last layer: emit bf16 of the final mean (atom_features, LINEAR)
        *(uint2*)&y1[ro + co] = pack4(sf.x, sf.y, sf.z, sf.w);
    }
    *(uint2*)&xb[ro + co] = pack4(o.x, o.y, o.z, o.w);
    y[t][0] = o.x; y[t][1] = o.y; y[t][2] = o.z; y[t][3] = o.w;
  }

  if (DOY12){
#pragma unroll
    for (int t=0;t<8;t++){
      int co = t*16 + quad*4;
      int po = (2 + (co>>6))*KP + (co&63);
      *(uint2*)&Ab[wrow + l15][po] = pack4(y[t][0], y[t][1], y[t][2], y[t][3]);
    }
    __syncthreads();                                  // B3: WN staged, y visible
    f32x4 a1[8], a2[8];
#pragma unroll
    for (int t=0;t<8;t++){ a1[t] = (f32x4)(0.f); a2[t] = (f32x4)(0.f); }
    NMFMA2(Ab, 2*KP, WB[0], 0,  a1)
    NMFMA2(Ab, 3*KP, WB[0], KP, a1)
    NMFMA2(Ab, 2*KP, WB[1], 0,  a2)
    NMFMA2(Ab, 3*KP, WB[1], KP, a2)
#pragma unroll
    for (int t=0;t<8;t++){
      int co = t*16 + quad*4;
      int pc = permc(co);
      *(uint2*)&y1[ro + pc] = pack4(
        a1[t][0]+b1s[co], a1[t][1]+b1s[co+1], a1[t][2]+b1s[co+2], a1[t][3]+b1s[co+3]);
      *(uint2*)&y2[ro + pc] = pack4(a2[t][0], a2[t][1], a2[t][2], a2[t][3]);
    }
  }
}

// FUSED tail: af -> h1=silu(ro1) -> ae=ro2 (f32 out) -> {h=silu(pn) -> hb,
// g = tanh(ae@gp1+b)@gp_w2+b2 -> gsc}
__global__ __launch_bounds__(256)
void k_tail(const u16* __restrict__ afb,
            const u16* __restrict__ Wro1, const float* __restrict__ bro1,
            const u16* __restrict__ Wro2, const float* __restrict__ bro2,
            const u16* __restrict__ Wpn,  const float* __restrict__ bpn,
            const u16* __restrict__ Wgp,  const float* __restrict__ bgp,
            const float* __restrict__ w2, const float* __restrict__ b2g,
            float* __restrict__ out_ae, u16* __restrict__ hb,
            float* __restrict__ g){
  __shared__ u16 Ab[TM][2*KP];
  __shared__ u16 WB[3][H][2*KP];
  __shared__ float r1b[H], r2b[H], pnb[H], g1b[H], w2s[H];
  const int tid = threadIdx.x;
  const int wave = tid>>6, l = tid&63, l15 = l&15, quad = l>>4;
  const int wrow = wave*16, q8 = quad*8;
  const int rowbase = blockIdx.x*TM;
  if (tid < H){ r1b[tid]=bro1[tid]; r2b[tid]=bro2[tid]; pnb[tid]=bpn[tid]; g1b[tid]=bgp[tid]; }
  else w2s[tid-H] = w2[tid-H];
  NSTAGE_W(WB[0], Wro1, 128, 0) NSTAGE_W(WB[0], Wro1, 128, 1)
  NSTAGE_W(WB[1], Wro2, 128, 0) NSTAGE_W(WB[1], Wro2, 128, 1)
  NSTAGE_W(WB[2], Wpn,  128, 0) NSTAGE_W(WB[2], Wpn,  128, 1)
  NSTAGE_A(Ab, afb + (size_t)rowbase*H, 0) NSTAGE_A(Ab, afb + (size_t)rowbase*H, 1)
  __syncthreads();                                    // B1
  f32x4 acc[8];
#pragma unroll
  for (int t=0;t<8;t++) acc[t] = (f32x4)(0.f);
  NMFMA2(Ab, 0, WB[0], 0, acc) NMFMA2(Ab, KP, WB[0], KP, acc)
#pragma unroll
  for (int t=0;t<8;t++){
    int co = t*16 + quad*4;
    int po = (co>>6)*KP + (co&63);
    *(uint2*)&Ab[wrow + l15][po] = pack4(
      siluf_(acc[t][0]+r1b[co]),   siluf_(acc[t][1]+r1b[co+1]),
      siluf_(acc[t][2]+r1b[co+2]), siluf_(acc[t][3]+r1b[co+3]));
  }
  __syncthreads();                                    // B2: WB[0] free, h1 visible
  NSTAGE_W(WB[0], Wgp, 128, 0) NSTAGE_W(WB[0], Wgp, 128, 1)
#pragma unroll
  for (int t=0;t<8;t++) acc[t] = (f32x4)(0.f);
  NMFMA2(Ab, 0, WB[1], 0, acc) NMFMA2(Ab, KP, WB[1], KP, acc)
  const int node = rowbase + wrow + l15;
  const size_t ro = (size_t)node*H;
#pragma unroll
  for (int t=0;t<8;t++){
    int co = t*16 + quad*4;
    float v0 = acc[t][0]+r2b[co],   v1 = acc[t][1]+r2b[co+1];
    float v2 = acc[t][2]+r2b[co+2], v3 = acc[t][3]+r2b[co+3];
    float4 o; o.x=v0; o.y=v1; o.z=v2; o.w=v3;
    *(float4*)&out_ae[ro + co] = o;
    int po = (co>>6)*KP + (co&63);
    *(uint2*)&Ab[wrow + l15][po] = pack4(v0,v1,v2,v3);
  }
  asm volatile("s_waitcnt lgkmcnt(0)" ::: "memory");
#pragma unroll
  for (int t=0;t<8;t++) acc[t] = (f32x4)(0.f);
  NMFMA2(Ab, 0, WB[2], 0, acc) NMFMA2(Ab, KP, WB[2], KP, acc)
#pragma unroll
  for (int t=0;t<8;t++){
    int co = t*16 + quad*4;
    *(uint2*)&hb[ro + co] = pack4(
      siluf_(acc[t][0]+pnb[co]),   siluf_(acc[t][1]+pnb[co+1]),
      siluf_(acc[t][2]+pnb[co+2]), siluf_(acc[t][3]+pnb[co+3]));
  }
  __syncthreads();                                    // B3: gp1 staged
#pragma unroll
  for (int t=0;t<8;t++) acc[t] = (f32x4)(0.f);
  NMFMA2(Ab, 0, WB[0], 0, acc) NMFMA2(Ab, KP, WB[0], KP, acc)
  float p = 0.f;
#pragma unroll
  for (int t=0;t<8;t++){
    int co = t*16 + quad*4;
#pragma unroll
    for (int r=0;r<4;r++) p = fmaf(tanhf(acc[t][r]+g1b[co+r]), w2s[co+r], p);
  }
  p += __shfl_xor(p, 16); p += __shfl_xor(p, 32);
  if (quad == 0) g[node] = p + b2g[0];
}

// ---------------------------------------------------------------- pooling
__global__ void k_start(const int* __restrict__ batch, int* __restrict__ start){
  int b = threadIdx.x;
  if (b > NB) return;
  if (b == NB){ start[NB] = NN; return; }
  int lo = 0, hi = NN;
  while (lo < hi){ int mid = (lo+hi) >> 1; if (batch[mid] < b) lo = mid+1; else hi = mid; }
  start[b] = lo;
}

// k_pool: PB blocks per batch; redundant gmax/den per block (g is L2-hot),
// node-slice weighted sum, one atomicAdd per column. out pre-zeroed.
__global__ __launch_bounds__(256)
void k_pool(const int* __restrict__ start, const float* __restrict__ g,
            const u16* __restrict__ hb, float* __restrict__ out){
  const int b   = blockIdx.x / PB;
  const int sub = blockIdx.x % PB;
  const int s = start[b], e = start[b+1];
  const int tid = threadIdx.x;
  __shared__ float red[4];
  __shared__ float s_gmax, s_den;
  __shared__ float part[2][H];

  float mx = -1e30f;
  for (int n = s + tid; n < e; n += 256) mx = fmaxf(mx, g[n]);
#pragma unroll
  for (int m=32;m>=1;m>>=1) mx = fmaxf(mx, __shfl_xor(mx, m, 64));
  if ((tid & 63) == 0) red[tid >> 6] = mx;
  __syncthreads();
  if (tid == 0){
    float v = fmaxf(fmaxf(red[0],red[1]), fmaxf(red[2],red[3]));
    s_gmax = (e > s) ? v : 0.0f;
  }
  __syncthreads();
  const float gmax = s_gmax;

  float sum = 0.f;
  for (int n = s + tid; n < e; n += 256) sum += __expf(g[n] - gmax);
#pragma unroll
  for (int m=32;m>=1;m>>=1) sum += __shfl_xor(sum, m, 64);
  if ((tid & 63) == 0) red[tid >> 6] = sum;
  __syncthreads();
  if (tid == 0) s_den = red[0]+red[1]+red[2]+red[3];
  __syncthreads();
  const float den = s_den;
  if (den <= 0.f) return;

  int len = e - s;
  int chunk = (len + PB - 1) / PB;
  int ns = s + sub*chunk;
  int ne = ns + chunk; if (ne > e) ne = e;
  if (ns >= ne) return;

  const int col = tid & 127, rg = tid >> 7;
  float acc = 0.f;
  for (int n = ns + rg; n < ne; n += 2)
    acc = fmaf(__expf(g[n] - gmax), bf2f(hb[(size_t)n*H + col]), acc);
  part[rg][col] = acc;
  __syncthreads();
  if (tid < H){
    float v = part[0][tid] + part[1][tid];
    if (v != 0.f) atomicAdd(&out[b*H + tid], v/den);
  }
}

// ================================================================ host
extern "C" void kernel_launch(void* const* d_in, const int* in_sizes, int n_in,
                              void* d_out, int out_size, void* d_ws, size_t ws_size,
                              hipStream_t stream){
  const int*   Z      = (const int*)  d_in[0];
  const float* pos    = (const float*)d_in[1];
  const int*   batch  = (const int*)  d_in[2];
  const int*   ei     = (const int*)  d_in[3];
  const float* embed  = (const float*)d_in[4];
  const float* widths = (const float*)d_in[5];
  const float* ee_w1  = (const float*)d_in[6];
  const float* ee_b1  = (const float*)d_in[7];
  const float* ee_w2  = (const float*)d_in[8];
  const float* ee_b2  = (const float*)d_in[9];
  const float* msg_w1 = (const float*)d_in[10];
  const float* msg_b1 = (const float*)d_in[11];
  const float* msg_w2 = (const float*)d_in[12];
  const float* msg_b2 = (const float*)d_in[13];
  const float* gate_w = (const float*)d_in[14];
  const float* gate_b = (const float*)d_in[15];
  const float* upd_w1 = (const float*)d_in[16];
  const float* upd_b1 = (const float*)d_in[17];
  const float* upd_w2 = (const float*)d_in[18];
  const float* upd_b2 = (const float*)d_in[19];
  const float* ln_g   = (const float*)d_in[20];
  const float* ln_b   = (const float*)d_in[21];
  const float* gp_w1  = (const float*)d_in[22];
  const float* gp_b1  = (const float*)d_in[23];
  const float* gp_w2  = (const float*)d_in[24];
  const float* gp_b2  = (const float*)d_in[25];
  const float* pn_w   = (const float*)d_in[26];
  const float* pn_b   = (const float*)d_in[27];
  const float* ro_w1  = (const float*)d_in[28];
  const float* ro_b1  = (const float*)d_in[29];
  const float* ro_w2  = (const float*)d_in[30];
  const float* ro_b2  = (const float*)d_in[31];

  const int* srcv = ei;
  const int* dstv = ei + NE;

  // ---- workspace carve (64B-aligned) — ~40 MB total
  char* p0 = (char*)d_ws;
  char* p = p0;
  auto carve = [&](size_t bytes)->char*{ char* q = p; p += (bytes + 63) & ~(size_t)63; return q; };
  float* x     = (float*)carve((size_t)NH*4);
  float* aggr  = (float*)carve((size_t)NH*4);
  float* gsc   = (float*)carve((size_t)NN*4);
  float* exb   = (float*)carve((size_t)NN*4);
  int*   startb  = (int*)carve((size_t)(NB+2)*4);
  int*   estart  = (int*)carve((size_t)(NN+1)*4);
  int*   ecursor = (int*)carve((size_t)NN*4);
  int*   src_s   = (int*)carve((size_t)NE*4);
  int*   dst_s   = (int*)carve((size_t)NE*4);
  u16*   xb      = (u16*)carve((size_t)NH*2);
  u16*   packw   = (u16*)carve((size_t)4*LT2*2);
  u16*   packn   = (u16*)carve((size_t)(NG+65536)*2);
  u16*   nb1     = (u16*)carve((size_t)NH*2);   // y1 during edge phase
  u16*   nb2     = (u16*)carve((size_t)NH*2);   // y2 during edge phase
  u16*   tab     = (u16*)carve((size_t)4*TT*TW*2);  // 8 MB: interleaved m1/gate tables

  float* out_af  = (float*)d_out;     // running sum of (feat/3) over last-3 layers
  float* out_ae  = out_af + NH;
  float* out_gaf = out_ae + NH;

  // ---- once-per-call prep
  k_pack<<<dim3((LT2+255)/256, 4), 256, 0, stream>>>(ee_w1, ee_w2, msg_w1, msg_w2, gate_w, packw);
  k_packn<<<(NG+65536+255)/256, 256, 0, stream>>>(upd_w1, upd_w2, ro_w1, ro_w2, pn_w, gp_w1, packn);
  k_table<<<dim3(TT/TM, 4), 256, 0, stream>>>(packw, widths, ee_b1, ee_b2, gate_b, tab);
  k_zero_i<<<(NN+255)/256, 256, 0, stream>>>(ecursor, NN);
  k_hist<<<NE/256, 256, 0, stream>>>(dstv, ecursor);
  k_scan<<<1, 1024, 0, stream>>>(ecursor, estart);
  k_scatter<<<NE/256, 256, 0, stream>>>(srcv, dstv, ecursor, src_s, dst_s);
  k_embed<<<NH/256, 256, 0, stream>>>(Z, embed, x, xb);
  k_zero<<<NH/256, 256, 0, stream>>>(out_af, NH);
  k_zero<<<(NB*H+255)/256, 256, 0, stream>>>(out_gaf, NB*H);
  k_zero<<<NH/256, 256, 0, stream>>>(aggr, NH);   // layer 0 only; k_upd re-zeros

  // layer-0 y1/y2 (subsequent layers fused into k_upd)
  k_y12<<<NN/TM, 256, 0, stream>>>(xb, packw + 82944, packw + 99328, msg_b1, nb1, nb2);

  for (int l=0; l<4; l++){
    const u16* pwn = packn + (size_t)l*LN_;
    const u16* pwN = packw + (size_t)(l+1)*LT2;   // next-layer edge pack (for fused y12)
    k_edge<<<NE/EPB, 256, 0, stream>>>(src_s, dst_s, pos, nb1, nb2,
                                       packw + (size_t)l*LT2 + (size_t)7*CHW,
                                       tab + (size_t)l*TT*TW,
                                       msg_b2 + l*H, aggr);
    if (l == 0)
      k_upd<0,1><<<NN/TM, 256, 0, stream>>>(aggr, xb, pwn, upd_b1 + l*H,
                                            pwn + 32768, upd_b2 + l*H,
                                            ln_g + l*H, ln_b + l*H, x, out_af, xb,
                                            pwN + 82944, pwN + 99328, msg_b1 + (l+1)*H,
                                            nb1, nb2);
    else if (l < 3)
      k_upd<1,1><<<NN/TM, 256, 0, stream>>>(aggr, xb, pwn, upd_b1 + l*H,
                                            pwn + 32768, upd_b2 + l*H,
                                            ln_g + l*H, ln_b + l*H, x, out_af, xb,
                                            pwN + 82944, pwN + 99328, msg_b1 + (l+1)*H,
                                            nb1, nb2);
    else
      k_upd<1,0><<<NN/TM, 256, 0, stream>>>(aggr, xb, pwn, upd_b1 + l*H,
                                            pwn + 32768, upd_b2 + l*H,
                                            ln_g + l*H, ln_b + l*H, x, out_af, xb,
                                            packw, packw, msg_b1,
                                            nb1, nb2);
  }

  // fused tail: nb1 = bf16(atom_features) from last k_upd (linear layout)
  k_tail<<<NN/TM, 256, 0, stream>>>(nb1,
                                    packn + NG,         ro_b1,
                                    packn + NG + 16384, ro_b2,
                                    packn + NG + 32768, pn_b,
                                    packn + NG + 49152, gp_b1, gp_w2, gp_b2,
                                    out_ae, nb2, gsc);
  k_start<<<1, 64, 0, stream>>>(batch, startb);
  k_pool<<<NB*PB, 256, 0, stream>>>(startb, gsc, nb2, out_gaf);
}